// Round 1
// baseline (933.419 us; speedup 1.0000x reference)
//
#include <hip/hip_runtime.h>
#include <hip/hip_bf16.h>
#include <math.h>

#define NN 50000
#define EE 800000
// NF=128, EF=64, S=128

// ---------------- deg histogram ----------------
__global__ void k_deg(const int* __restrict__ ei, int* __restrict__ deg) {
    int e = blockIdx.x * 256 + threadIdx.x;
    if (e < EE) atomicAdd(&deg[ei[EE + e]], 1);
}

// ---------------- weight prep: Wcat[i][2k]=Wzc@Wzl_top, [2k+1]=Whc@Whl_top; cb ----------------
__global__ void k_wprep(const float* __restrict__ Wzc, const float* __restrict__ bzc,
                        const float* __restrict__ Wzl, const float* __restrict__ bzl,
                        const float* __restrict__ Whc, const float* __restrict__ bhc,
                        const float* __restrict__ Whl, const float* __restrict__ bhl,
                        float* __restrict__ Wcat, float* __restrict__ cb) {
    int k = blockIdx.x;      // 0..127 output col
    int i = threadIdx.x;     // 0..127 input row
    float sz = 0.f, sh = 0.f;
    for (int j = 0; j < 128; j++) {
        sz += Wzc[i * 128 + j] * Wzl[j * 128 + k];
        sh += Whc[i * 128 + j] * Whl[j * 128 + k];
    }
    Wcat[i * 256 + 2 * k]     = sz;
    Wcat[i * 256 + 2 * k + 1] = sh;
    if (i == 0) {
        float bz = bzl[k], bh = bhl[k];
        for (int j = 0; j < 128; j++) {
            bz += bzc[j] * Wzl[j * 128 + k];
            bh += bhc[j] * Whl[j * 128 + k];
        }
        cb[2 * k]     = bz;
        cb[2 * k + 1] = bh;
    }
}

// ---------------- tiled fp32 GEMM: C[M,NC] = f(A[M,128] @ B[128,NC]) ----------------
// RELU: add bias then relu.  SCALE: multiply row by rsqrt(deg+1).
template <int NC, bool RELU, bool SCALE>
__global__ __launch_bounds__(256) void k_gemm(const float* __restrict__ A,
                                              const float* __restrict__ B,
                                              const float* __restrict__ bias,
                                              const int* __restrict__ deg,
                                              float* __restrict__ C, int M) {
    __shared__ float As[8][128];
    __shared__ float Bs[8][128];
    const int m0 = blockIdx.x * 128;
    const int n0 = blockIdx.y * 128;
    const int tid = threadIdx.x;
    const int tx = tid & 15;   // col lane
    const int ty = tid >> 4;   // row lane
    float acc[8][8];
#pragma unroll
    for (int i = 0; i < 8; i++)
#pragma unroll
        for (int j = 0; j < 8; j++) acc[i][j] = 0.f;

    for (int k0 = 0; k0 < 128; k0 += 8) {
        // stage A chunk (128 rows x 8 k), transposed into As[kk][m]
        {
            int m = tid >> 1, kk = (tid & 1) * 4;
            float4 av = make_float4(0.f, 0.f, 0.f, 0.f);
            if (m0 + m < M) av = *(const float4*)&A[(size_t)(m0 + m) * 128 + k0 + kk];
            As[kk + 0][m] = av.x; As[kk + 1][m] = av.y;
            As[kk + 2][m] = av.z; As[kk + 3][m] = av.w;
        }
        // stage B chunk (8 k x 128 cols)
        {
            int kb = tid >> 5, n = (tid & 31) * 4;
            float4 bv = *(const float4*)&B[(size_t)(k0 + kb) * NC + n0 + n];
            *(float4*)&Bs[kb][n] = bv;
        }
        __syncthreads();
#pragma unroll
        for (int kk = 0; kk < 8; kk++) {
            float af[8], bf[8];
#pragma unroll
            for (int i = 0; i < 8; i++) af[i] = As[kk][ty + 16 * i];
#pragma unroll
            for (int j = 0; j < 8; j++) bf[j] = Bs[kk][tx + 16 * j];
#pragma unroll
            for (int i = 0; i < 8; i++)
#pragma unroll
                for (int j = 0; j < 8; j++) acc[i][j] += af[i] * bf[j];
        }
        __syncthreads();
    }
#pragma unroll
    for (int i = 0; i < 8; i++) {
        int row = m0 + ty + 16 * i;
        if (row >= M) continue;
        float di = 1.f;
        if (SCALE) di = rsqrtf((float)(deg[row] + 1));
#pragma unroll
        for (int j = 0; j < 8; j++) {
            int cg = n0 + tx + 16 * j;
            float v = acc[i][j];
            if (RELU) v = fmaxf(v + bias[cg], 0.f);
            if (SCALE) v *= di;
            C[(size_t)row * NC + cg] = v;
        }
    }
}

// ---------------- scan (3-pass) for CSR rowptr ----------------
__global__ void k_scan_a(const int* __restrict__ deg, int* __restrict__ partial) {
    __shared__ int s[256];
    int i = blockIdx.x * 256 + threadIdx.x;
    s[threadIdx.x] = (i < NN) ? deg[i] : 0;
    __syncthreads();
    for (int off = 128; off > 0; off >>= 1) {
        if (threadIdx.x < off) s[threadIdx.x] += s[threadIdx.x + off];
        __syncthreads();
    }
    if (threadIdx.x == 0) partial[blockIdx.x] = s[0];
}

__global__ void k_scan_b(const int* __restrict__ partial, int* __restrict__ partoff, int nb) {
    __shared__ int s[256];
    int v = (threadIdx.x < nb) ? partial[threadIdx.x] : 0;
    s[threadIdx.x] = v;
    __syncthreads();
    for (int off = 1; off < 256; off <<= 1) {
        int t = (threadIdx.x >= off) ? s[threadIdx.x - off] : 0;
        __syncthreads();
        s[threadIdx.x] += t;
        __syncthreads();
    }
    partoff[threadIdx.x] = s[threadIdx.x] - v;  // exclusive
}

__global__ void k_scan_c(const int* __restrict__ deg, const int* __restrict__ partoff,
                         int* __restrict__ rowptr, int* __restrict__ cursor) {
    __shared__ int s[256];
    int i = blockIdx.x * 256 + threadIdx.x;
    int v = (i < NN) ? deg[i] : 0;
    s[threadIdx.x] = v;
    __syncthreads();
    for (int off = 1; off < 256; off <<= 1) {
        int t = (threadIdx.x >= off) ? s[threadIdx.x - off] : 0;
        __syncthreads();
        s[threadIdx.x] += t;
        __syncthreads();
    }
    int excl = s[threadIdx.x] - v + partoff[blockIdx.x];
    if (i < NN) { rowptr[i] = excl; cursor[i] = excl; }
    if (i == 0) rowptr[NN] = EE;
}

__global__ void k_fill(const int* __restrict__ ei, int* __restrict__ cursor,
                       int* __restrict__ col) {
    int e = blockIdx.x * 256 + threadIdx.x;
    if (e < EE) {
        int d = ei[EE + e];
        int p = atomicAdd(&cursor[d], 1);
        col[p] = ei[e];
    }
}

// ---------------- per-node gather: one wave per node ----------------
// PQ rows are dinv[src]-prescaled; interleaved cols: 2k = z-gate, 2k+1 = h-gate.
__global__ __launch_bounds__(256) void k_gather(const float* __restrict__ PQ,
                                                const int* __restrict__ rowptr,
                                                const int* __restrict__ col,
                                                const int* __restrict__ deg,
                                                const float* __restrict__ Wout,
                                                const float* __restrict__ cb,
                                                float* __restrict__ aArr,
                                                float* __restrict__ bArr) {
    int gt = blockIdx.x * 256 + threadIdx.x;
    int node = gt >> 6;
    int lane = threadIdx.x & 63;
    if (node >= NN) return;
    int beg = rowptr[node], end = rowptr[node + 1];
    const float4* selfrow = (const float4*)(PQ + (size_t)node * 256);
    float4 acc = selfrow[lane];  // self loop term
    for (int p = beg; p < end; p += 64) {
        int chunk = min(64, end - p);
        int cv = (p + lane < end) ? col[p + lane] : 0;
        for (int j = 0; j < chunk; j++) {
            int s = __shfl(cv, j);
            float4 v = ((const float4*)(PQ + (size_t)s * 256))[lane];
            acc.x += v.x; acc.y += v.y; acc.z += v.z; acc.w += v.w;
        }
    }
    float di = rsqrtf((float)(deg[node] + 1));
    int c0 = 4 * lane;
    float z0 = 1.f / (1.f + expf(-(acc.x * di + cb[c0 + 0])));
    float t0 = tanhf(acc.y * di + cb[c0 + 1]);
    float z1 = 1.f / (1.f + expf(-(acc.z * di + cb[c0 + 2])));
    float t1 = tanhf(acc.w * di + cb[c0 + 3]);
    float h0 = (1.f - z0) * t0;
    float h1 = (1.f - z1) * t1;
    int k0 = 2 * lane, k1 = 2 * lane + 1;
    float pa = h0 * Wout[k0] + h1 * Wout[k1];
    float pb = h0 * Wout[128 + k0] + h1 * Wout[128 + k1];
#pragma unroll
    for (int off = 32; off > 0; off >>= 1) {
        pa += __shfl_down(pa, off);
        pb += __shfl_down(pb, off);
    }
    if (lane == 0) { aArr[node] = pa; bArr[node] = pb; }
}

// ---------------- per-edge fused GEMV: c = relu(attr@We+be)·w3; out = a[src]+b[dst]+c+bout ----------------
__global__ __launch_bounds__(256) void k_edge(const float* __restrict__ EA,
                                              const int* __restrict__ ei,
                                              const float* __restrict__ We,
                                              const float* __restrict__ be,
                                              const float* __restrict__ Wout,
                                              const float* __restrict__ boutp,
                                              const float* __restrict__ aArr,
                                              const float* __restrict__ bArr,
                                              float* __restrict__ out) {
    __shared__ float WeT[128 * 64];  // [k][i]
    __shared__ float beL[128], w3L[128];
    int tid = threadIdx.x;
    for (int idx = tid; idx < 8192; idx += 256) {
        int i = idx >> 7, k = idx & 127;
        WeT[k * 64 + i] = We[idx];
    }
    if (tid < 128) { beL[tid] = be[tid]; w3L[tid] = Wout[256 + tid]; }
    __syncthreads();
    int e = blockIdx.x * 256 + tid;
    float4 a4[16];
#pragma unroll
    for (int i = 0; i < 16; i++) a4[i] = *(const float4*)&EA[(size_t)e * 64 + i * 4];
    float c = 0.f;
    for (int k = 0; k < 128; k++) {
        float y = beL[k];
        const float4* w = (const float4*)&WeT[k * 64];
#pragma unroll
        for (int i = 0; i < 16; i++) {
            float4 wv = w[i];
            y += a4[i].x * wv.x + a4[i].y * wv.y + a4[i].z * wv.z + a4[i].w * wv.w;
        }
        c += fmaxf(y, 0.f) * w3L[k];
    }
    int s = ei[e], d = ei[EE + e];
    out[e] = aArr[s] + bArr[d] + c + boutp[0];
}

extern "C" void kernel_launch(void* const* d_in, const int* in_sizes, int n_in,
                              void* d_out, int out_size, void* d_ws, size_t ws_size,
                              hipStream_t stream) {
    const float* x    = (const float*)d_in[0];
    const int*   ei   = (const int*)d_in[1];
    const float* ea   = (const float*)d_in[2];
    const float* Wn   = (const float*)d_in[3];
    const float* bn   = (const float*)d_in[4];
    const float* We   = (const float*)d_in[5];
    const float* be   = (const float*)d_in[6];
    const float* Wzc  = (const float*)d_in[7];
    const float* bzc  = (const float*)d_in[8];
    const float* Wzl  = (const float*)d_in[9];
    const float* bzl  = (const float*)d_in[10];
    const float* Whc  = (const float*)d_in[15];
    const float* bhc  = (const float*)d_in[16];
    const float* Whl  = (const float*)d_in[17];
    const float* bhl  = (const float*)d_in[18];
    const float* Wout = (const float*)d_in[19];
    const float* bout = (const float*)d_in[20];
    float* out = (float*)d_out;

    // workspace carve (256B aligned)
    char* w = (char*)d_ws;
    auto carve = [&](size_t bytes) {
        void* p = (void*)w;
        w += (bytes + 255) / 256 * 256;
        return p;
    };
    float* xe      = (float*)carve((size_t)NN * 128 * 4);
    float* PQ      = (float*)carve((size_t)NN * 256 * 4);
    float* Wcat    = (float*)carve(128 * 256 * 4);
    float* cb      = (float*)carve(256 * 4);
    int*   deg     = (int*)carve((size_t)NN * 4);
    int*   rowptr  = (int*)carve((size_t)(NN + 1) * 4);
    int*   cursor  = (int*)carve((size_t)NN * 4);
    int*   col     = (int*)carve((size_t)EE * 4);
    int*   partial = (int*)carve(256 * 4);
    int*   partoff = (int*)carve(256 * 4);
    float* aArr    = (float*)carve((size_t)NN * 4);
    float* bArr    = (float*)carve((size_t)NN * 4);

    hipMemsetAsync(deg, 0, (size_t)NN * 4, stream);
    k_deg<<<(EE + 255) / 256, 256, 0, stream>>>(ei, deg);
    k_wprep<<<128, 128, 0, stream>>>(Wzc, bzc, Wzl, bzl, Whc, bhc, Whl, bhl, Wcat, cb);

    // xe = relu(x @ Wn + bn)
    k_gemm<128, true, false><<<dim3(391, 1), 256, 0, stream>>>(x, Wn, bn, deg, xe, NN);
    // PQ = (xe @ Wcat) * dinv[row]   (cols interleaved z/h)
    k_gemm<256, false, true><<<dim3(391, 2), 256, 0, stream>>>(xe, Wcat, nullptr, deg, PQ, NN);

    // CSR build
    const int NB = (NN + 255) / 256;  // 196
    k_scan_a<<<NB, 256, 0, stream>>>(deg, partial);
    k_scan_b<<<1, 256, 0, stream>>>(partial, partoff, NB);
    k_scan_c<<<NB, 256, 0, stream>>>(deg, partoff, rowptr, cursor);
    k_fill<<<(EE + 255) / 256, 256, 0, stream>>>(ei, cursor, col);

    // per-node gather -> a,b scalars
    k_gather<<<(NN * 64 + 255) / 256, 256, 0, stream>>>(PQ, rowptr, col, deg, Wout, cb, aArr, bArr);

    // per-edge fused output
    k_edge<<<EE / 256, 256, 0, stream>>>(ea, ei, We, be, Wout, bout, aArr, bArr, out);
}

// Round 2
// 680.808 us; speedup vs baseline: 1.3710x; 1.3710x over previous
//
#include <hip/hip_runtime.h>
#include <hip/hip_bf16.h>
#include <math.h>

#define NN 50000
#define EE 800000
// NF=128, EF=64, S=128

typedef __bf16 bf16x8 __attribute__((ext_vector_type(8)));
typedef float f32x4 __attribute__((ext_vector_type(4)));

// ---------------- deg histogram ----------------
__global__ void k_deg(const int* __restrict__ ei, int* __restrict__ deg) {
    int e = blockIdx.x * 256 + threadIdx.x;
    if (e < EE) atomicAdd(&deg[ei[EE + e]], 1);
}

// ---------------- weight prep: Wcat[i][2k]=Wzc@Wzl_top, [2k+1]=Whc@Whl_top; cb ----------------
__global__ void k_wprep(const float* __restrict__ Wzc, const float* __restrict__ bzc,
                        const float* __restrict__ Wzl, const float* __restrict__ bzl,
                        const float* __restrict__ Whc, const float* __restrict__ bhc,
                        const float* __restrict__ Whl, const float* __restrict__ bhl,
                        float* __restrict__ Wcat, float* __restrict__ cb) {
    int k = blockIdx.x;      // 0..127 output col
    int i = threadIdx.x;     // 0..127 input row
    float sz = 0.f, sh = 0.f;
    for (int j = 0; j < 128; j++) {
        sz += Wzc[i * 128 + j] * Wzl[j * 128 + k];
        sh += Whc[i * 128 + j] * Whl[j * 128 + k];
    }
    Wcat[i * 256 + 2 * k]     = sz;
    Wcat[i * 256 + 2 * k + 1] = sh;
    if (i == 0) {
        float bz = bzl[k], bh = bhl[k];
        for (int j = 0; j < 128; j++) {
            bz += bzc[j] * Wzl[j * 128 + k];
            bh += bhc[j] * Whl[j * 128 + k];
        }
        cb[2 * k]     = bz;
        cb[2 * k + 1] = bh;
    }
}

// ---------------- tiled fp32 GEMM: C[M,NC] = f(A[M,128] @ B[128,NC]) ----------------
template <int NC, bool RELU, bool SCALE>
__global__ __launch_bounds__(256) void k_gemm(const float* __restrict__ A,
                                              const float* __restrict__ B,
                                              const float* __restrict__ bias,
                                              const int* __restrict__ deg,
                                              float* __restrict__ C, int M) {
    __shared__ float As[8][128];
    __shared__ float Bs[8][128];
    const int m0 = blockIdx.x * 128;
    const int n0 = blockIdx.y * 128;
    const int tid = threadIdx.x;
    const int tx = tid & 15;   // col lane
    const int ty = tid >> 4;   // row lane
    float acc[8][8];
#pragma unroll
    for (int i = 0; i < 8; i++)
#pragma unroll
        for (int j = 0; j < 8; j++) acc[i][j] = 0.f;

    for (int k0 = 0; k0 < 128; k0 += 8) {
        {
            int m = tid >> 1, kk = (tid & 1) * 4;
            float4 av = make_float4(0.f, 0.f, 0.f, 0.f);
            if (m0 + m < M) av = *(const float4*)&A[(size_t)(m0 + m) * 128 + k0 + kk];
            As[kk + 0][m] = av.x; As[kk + 1][m] = av.y;
            As[kk + 2][m] = av.z; As[kk + 3][m] = av.w;
        }
        {
            int kb = tid >> 5, n = (tid & 31) * 4;
            float4 bv = *(const float4*)&B[(size_t)(k0 + kb) * NC + n0 + n];
            *(float4*)&Bs[kb][n] = bv;
        }
        __syncthreads();
#pragma unroll
        for (int kk = 0; kk < 8; kk++) {
            float af[8], bf[8];
#pragma unroll
            for (int i = 0; i < 8; i++) af[i] = As[kk][ty + 16 * i];
#pragma unroll
            for (int j = 0; j < 8; j++) bf[j] = Bs[kk][tx + 16 * j];
#pragma unroll
            for (int i = 0; i < 8; i++)
#pragma unroll
                for (int j = 0; j < 8; j++) acc[i][j] += af[i] * bf[j];
        }
        __syncthreads();
    }
#pragma unroll
    for (int i = 0; i < 8; i++) {
        int row = m0 + ty + 16 * i;
        if (row >= M) continue;
        float di = 1.f;
        if (SCALE) di = rsqrtf((float)(deg[row] + 1));
#pragma unroll
        for (int j = 0; j < 8; j++) {
            int cg = n0 + tx + 16 * j;
            float v = acc[i][j];
            if (RELU) v = fmaxf(v + bias[cg], 0.f);
            if (SCALE) v *= di;
            C[(size_t)row * NC + cg] = v;
        }
    }
}

// ---------------- scan (3-pass) for CSR rowptr ----------------
__global__ void k_scan_a(const int* __restrict__ deg, int* __restrict__ partial) {
    __shared__ int s[256];
    int i = blockIdx.x * 256 + threadIdx.x;
    s[threadIdx.x] = (i < NN) ? deg[i] : 0;
    __syncthreads();
    for (int off = 128; off > 0; off >>= 1) {
        if (threadIdx.x < off) s[threadIdx.x] += s[threadIdx.x + off];
        __syncthreads();
    }
    if (threadIdx.x == 0) partial[blockIdx.x] = s[0];
}

__global__ void k_scan_b(const int* __restrict__ partial, int* __restrict__ partoff, int nb) {
    __shared__ int s[256];
    int v = (threadIdx.x < nb) ? partial[threadIdx.x] : 0;
    s[threadIdx.x] = v;
    __syncthreads();
    for (int off = 1; off < 256; off <<= 1) {
        int t = (threadIdx.x >= off) ? s[threadIdx.x - off] : 0;
        __syncthreads();
        s[threadIdx.x] += t;
        __syncthreads();
    }
    partoff[threadIdx.x] = s[threadIdx.x] - v;  // exclusive
}

__global__ void k_scan_c(const int* __restrict__ deg, const int* __restrict__ partoff,
                         int* __restrict__ rowptr, int* __restrict__ cursor) {
    __shared__ int s[256];
    int i = blockIdx.x * 256 + threadIdx.x;
    int v = (i < NN) ? deg[i] : 0;
    s[threadIdx.x] = v;
    __syncthreads();
    for (int off = 1; off < 256; off <<= 1) {
        int t = (threadIdx.x >= off) ? s[threadIdx.x - off] : 0;
        __syncthreads();
        s[threadIdx.x] += t;
        __syncthreads();
    }
    int excl = s[threadIdx.x] - v + partoff[blockIdx.x];
    if (i < NN) { rowptr[i] = excl; cursor[i] = excl; }
    if (i == 0) rowptr[NN] = EE;
}

__global__ void k_fill(const int* __restrict__ ei, int* __restrict__ cursor,
                       int* __restrict__ col) {
    int e = blockIdx.x * 256 + threadIdx.x;
    if (e < EE) {
        int d = ei[EE + e];
        int p = atomicAdd(&cursor[d], 1);
        col[p] = ei[e];
    }
}

// ---------------- per-node gather: one wave per node ----------------
__global__ __launch_bounds__(256) void k_gather(const float* __restrict__ PQ,
                                                const int* __restrict__ rowptr,
                                                const int* __restrict__ col,
                                                const int* __restrict__ deg,
                                                const float* __restrict__ Wout,
                                                const float* __restrict__ cb,
                                                float* __restrict__ aArr,
                                                float* __restrict__ bArr) {
    int gt = blockIdx.x * 256 + threadIdx.x;
    int node = gt >> 6;
    int lane = threadIdx.x & 63;
    if (node >= NN) return;
    int beg = rowptr[node], end = rowptr[node + 1];
    const float4* selfrow = (const float4*)(PQ + (size_t)node * 256);
    float4 acc = selfrow[lane];  // self loop term
    for (int p = beg; p < end; p += 64) {
        int chunk = min(64, end - p);
        int cv = (p + lane < end) ? col[p + lane] : 0;
        for (int j = 0; j < chunk; j++) {
            int s = __shfl(cv, j);
            float4 v = ((const float4*)(PQ + (size_t)s * 256))[lane];
            acc.x += v.x; acc.y += v.y; acc.z += v.z; acc.w += v.w;
        }
    }
    float di = rsqrtf((float)(deg[node] + 1));
    int c0 = 4 * lane;
    float z0 = 1.f / (1.f + expf(-(acc.x * di + cb[c0 + 0])));
    float t0 = tanhf(acc.y * di + cb[c0 + 1]);
    float z1 = 1.f / (1.f + expf(-(acc.z * di + cb[c0 + 2])));
    float t1 = tanhf(acc.w * di + cb[c0 + 3]);
    float h0 = (1.f - z0) * t0;
    float h1 = (1.f - z1) * t1;
    int k0 = 2 * lane, k1 = 2 * lane + 1;
    float pa = h0 * Wout[k0] + h1 * Wout[k1];
    float pb = h0 * Wout[128 + k0] + h1 * Wout[128 + k1];
#pragma unroll
    for (int off = 32; off > 0; off >>= 1) {
        pa += __shfl_down(pa, off);
        pb += __shfl_down(pb, off);
    }
    if (lane == 0) { aArr[node] = pa; bArr[node] = pb; }
}

// ---------------- per-edge fused GEMM via MFMA ----------------
// C[E,128] = relu(EA[E,64]@We[64,128] + be); c[e] = C[e,:]·w3; out = a[src]+b[dst]+c+bout
// One wave per 16-edge tile. We/be/w3 preloaded into loop-invariant registers.
__global__ __launch_bounds__(256) void k_edge_mfma(const float* __restrict__ EA,
                                                   const int* __restrict__ ei,
                                                   const float* __restrict__ We,
                                                   const float* __restrict__ be,
                                                   const float* __restrict__ Wout,
                                                   const float* __restrict__ boutp,
                                                   const float* __restrict__ aArr,
                                                   const float* __restrict__ bArr,
                                                   float* __restrict__ out) {
    const int lane = threadIdx.x & 63;
    const int ln = lane & 15;      // col / edge-row selector
    const int q  = lane >> 4;      // quad
    const int wid = (blockIdx.x * 256 + threadIdx.x) >> 6;
    const int nw  = gridDim.x * 4;

    // B fragments: bfrag[h][t][j] = We[h*32 + q*8 + j][t*16 + ln]  (loop-invariant)
    bf16x8 bfrag[2][8];
#pragma unroll
    for (int h = 0; h < 2; h++)
#pragma unroll
        for (int t = 0; t < 8; t++)
#pragma unroll
            for (int j = 0; j < 8; j++)
                bfrag[h][t][j] = (__bf16)We[(h * 32 + q * 8 + j) * 128 + t * 16 + ln];

    float beR[8], w3R[8];
#pragma unroll
    for (int t = 0; t < 8; t++) {
        beR[t] = be[t * 16 + ln];
        w3R[t] = Wout[256 + t * 16 + ln];
    }
    const float b0 = boutp[0];

    for (int tile = wid; tile < EE / 16; tile += nw) {
        const int e0 = tile * 16;
        const float* arow = EA + (size_t)(e0 + ln) * 64;
        // A fragments: afrag[h][j] = EA[e0+ln][h*32 + q*8 + j]
        float4 v0 = *(const float4*)(arow + q * 8);
        float4 v1 = *(const float4*)(arow + q * 8 + 4);
        float4 v2 = *(const float4*)(arow + 32 + q * 8);
        float4 v3 = *(const float4*)(arow + 32 + q * 8 + 4);
        bf16x8 af0, af1;
        af0[0] = (__bf16)v0.x; af0[1] = (__bf16)v0.y; af0[2] = (__bf16)v0.z; af0[3] = (__bf16)v0.w;
        af0[4] = (__bf16)v1.x; af0[5] = (__bf16)v1.y; af0[6] = (__bf16)v1.z; af0[7] = (__bf16)v1.w;
        af1[0] = (__bf16)v2.x; af1[1] = (__bf16)v2.y; af1[2] = (__bf16)v2.z; af1[3] = (__bf16)v2.w;
        af1[4] = (__bf16)v3.x; af1[5] = (__bf16)v3.y; af1[6] = (__bf16)v3.z; af1[7] = (__bf16)v3.w;

        f32x4 acc[8];
#pragma unroll
        for (int t = 0; t < 8; t++) acc[t] = (f32x4){0.f, 0.f, 0.f, 0.f};
#pragma unroll
        for (int t = 0; t < 8; t++)
            acc[t] = __builtin_amdgcn_mfma_f32_16x16x32_bf16(af0, bfrag[0][t], acc[t], 0, 0, 0);
#pragma unroll
        for (int t = 0; t < 8; t++)
            acc[t] = __builtin_amdgcn_mfma_f32_16x16x32_bf16(af1, bfrag[1][t], acc[t], 0, 0, 0);

        // epilogue: relu(+be) · w3, per lane covers cols t*16+ln, rows q*4+r
        float part[4] = {0.f, 0.f, 0.f, 0.f};
#pragma unroll
        for (int t = 0; t < 8; t++)
#pragma unroll
            for (int r = 0; r < 4; r++) {
                float y = acc[t][r] + beR[t];
                y = fmaxf(y, 0.f);
                part[r] += y * w3R[t];
            }
        // reduce across the 16 lanes within the quad (cols)
#pragma unroll
        for (int off = 1; off < 16; off <<= 1) {
#pragma unroll
            for (int r = 0; r < 4; r++) part[r] += __shfl_xor(part[r], off);
        }
        if (ln < 4) {
            float c = (ln == 0) ? part[0] : (ln == 1) ? part[1] : (ln == 2) ? part[2] : part[3];
            int e = e0 + q * 4 + ln;   // row m = q*4 + r
            out[e] = c + aArr[ei[e]] + bArr[ei[EE + e]] + b0;
        }
    }
}

extern "C" void kernel_launch(void* const* d_in, const int* in_sizes, int n_in,
                              void* d_out, int out_size, void* d_ws, size_t ws_size,
                              hipStream_t stream) {
    const float* x    = (const float*)d_in[0];
    const int*   ei   = (const int*)d_in[1];
    const float* ea   = (const float*)d_in[2];
    const float* Wn   = (const float*)d_in[3];
    const float* bn   = (const float*)d_in[4];
    const float* We   = (const float*)d_in[5];
    const float* be   = (const float*)d_in[6];
    const float* Wzc  = (const float*)d_in[7];
    const float* bzc  = (const float*)d_in[8];
    const float* Wzl  = (const float*)d_in[9];
    const float* bzl  = (const float*)d_in[10];
    const float* Whc  = (const float*)d_in[15];
    const float* bhc  = (const float*)d_in[16];
    const float* Whl  = (const float*)d_in[17];
    const float* bhl  = (const float*)d_in[18];
    const float* Wout = (const float*)d_in[19];
    const float* bout = (const float*)d_in[20];
    float* out = (float*)d_out;

    char* w = (char*)d_ws;
    auto carve = [&](size_t bytes) {
        void* p = (void*)w;
        w += (bytes + 255) / 256 * 256;
        return p;
    };
    float* xe      = (float*)carve((size_t)NN * 128 * 4);
    float* PQ      = (float*)carve((size_t)NN * 256 * 4);
    float* Wcat    = (float*)carve(128 * 256 * 4);
    float* cb      = (float*)carve(256 * 4);
    int*   deg     = (int*)carve((size_t)NN * 4);
    int*   rowptr  = (int*)carve((size_t)(NN + 1) * 4);
    int*   cursor  = (int*)carve((size_t)NN * 4);
    int*   col     = (int*)carve((size_t)EE * 4);
    int*   partial = (int*)carve(256 * 4);
    int*   partoff = (int*)carve(256 * 4);
    float* aArr    = (float*)carve((size_t)NN * 4);
    float* bArr    = (float*)carve((size_t)NN * 4);

    hipMemsetAsync(deg, 0, (size_t)NN * 4, stream);
    k_deg<<<(EE + 255) / 256, 256, 0, stream>>>(ei, deg);
    k_wprep<<<128, 128, 0, stream>>>(Wzc, bzc, Wzl, bzl, Whc, bhc, Whl, bhl, Wcat, cb);

    k_gemm<128, true, false><<<dim3(391, 1), 256, 0, stream>>>(x, Wn, bn, deg, xe, NN);
    k_gemm<256, false, true><<<dim3(391, 2), 256, 0, stream>>>(xe, Wcat, nullptr, deg, PQ, NN);

    const int NB = (NN + 255) / 256;  // 196
    k_scan_a<<<NB, 256, 0, stream>>>(deg, partial);
    k_scan_b<<<1, 256, 0, stream>>>(partial, partoff, NB);
    k_scan_c<<<NB, 256, 0, stream>>>(deg, partoff, rowptr, cursor);
    k_fill<<<(EE + 255) / 256, 256, 0, stream>>>(ei, cursor, col);

    k_gather<<<(NN * 64 + 255) / 256, 256, 0, stream>>>(PQ, rowptr, col, deg, Wout, cb, aArr, bArr);

    k_edge_mfma<<<1024, 256, 0, stream>>>(ea, ei, We, be, Wout, bout, aArr, bArr, out);
}

// Round 3
// 653.876 us; speedup vs baseline: 1.4275x; 1.0412x over previous
//
#include <hip/hip_runtime.h>
#include <hip/hip_bf16.h>
#include <math.h>

#define NN 50000
#define EE 800000
// NF=128, EF=64, S=128

typedef __bf16 bf16x8 __attribute__((ext_vector_type(8)));
typedef float f32x4 __attribute__((ext_vector_type(4)));

// ---------------- deg histogram ----------------
__global__ void k_deg(const int* __restrict__ ei, int* __restrict__ deg) {
    int e = blockIdx.x * 256 + threadIdx.x;
    if (e < EE) atomicAdd(&deg[ei[EE + e]], 1);
}

// ---------------- weight prep: Wcat[i][2k]=Wzc@Wzl_top, [2k+1]=Whc@Whl_top; cb ----------------
__global__ void k_wprep(const float* __restrict__ Wzc, const float* __restrict__ bzc,
                        const float* __restrict__ Wzl, const float* __restrict__ bzl,
                        const float* __restrict__ Whc, const float* __restrict__ bhc,
                        const float* __restrict__ Whl, const float* __restrict__ bhl,
                        float* __restrict__ Wcat, float* __restrict__ cb) {
    int k = blockIdx.x;      // 0..127 output col
    int i = threadIdx.x;     // 0..127 input row
    float sz = 0.f, sh = 0.f;
    for (int j = 0; j < 128; j++) {
        sz += Wzc[i * 128 + j] * Wzl[j * 128 + k];
        sh += Whc[i * 128 + j] * Whl[j * 128 + k];
    }
    Wcat[i * 256 + 2 * k]     = sz;
    Wcat[i * 256 + 2 * k + 1] = sh;
    if (i == 0) {
        float bz = bzl[k], bh = bhl[k];
        for (int j = 0; j < 128; j++) {
            bz += bzc[j] * Wzl[j * 128 + k];
            bh += bhc[j] * Whl[j * 128 + k];
        }
        cb[2 * k]     = bz;
        cb[2 * k + 1] = bh;
    }
}

// ---------------- GEMM1: xs[M,128] = relu(x @ Wn + bn) * dinv[row] ----------------
__global__ __launch_bounds__(256) void k_gemm1(const float* __restrict__ A,
                                               const float* __restrict__ B,
                                               const float* __restrict__ bias,
                                               const int* __restrict__ deg,
                                               float* __restrict__ C, int M) {
    __shared__ float As[8][128];
    __shared__ float Bs[8][128];
    const int m0 = blockIdx.x * 128;
    const int tid = threadIdx.x;
    const int tx = tid & 15;
    const int ty = tid >> 4;
    float acc[8][8];
#pragma unroll
    for (int i = 0; i < 8; i++)
#pragma unroll
        for (int j = 0; j < 8; j++) acc[i][j] = 0.f;

    for (int k0 = 0; k0 < 128; k0 += 8) {
        {
            int m = tid >> 1, kk = (tid & 1) * 4;
            float4 av = make_float4(0.f, 0.f, 0.f, 0.f);
            if (m0 + m < M) av = *(const float4*)&A[(size_t)(m0 + m) * 128 + k0 + kk];
            As[kk + 0][m] = av.x; As[kk + 1][m] = av.y;
            As[kk + 2][m] = av.z; As[kk + 3][m] = av.w;
        }
        {
            int kb = tid >> 5, n = (tid & 31) * 4;
            float4 bv = *(const float4*)&B[(size_t)(k0 + kb) * 128 + n];
            *(float4*)&Bs[kb][n] = bv;
        }
        __syncthreads();
#pragma unroll
        for (int kk = 0; kk < 8; kk++) {
            float af[8], bf[8];
#pragma unroll
            for (int i = 0; i < 8; i++) af[i] = As[kk][ty + 16 * i];
#pragma unroll
            for (int j = 0; j < 8; j++) bf[j] = Bs[kk][tx + 16 * j];
#pragma unroll
            for (int i = 0; i < 8; i++)
#pragma unroll
                for (int j = 0; j < 8; j++) acc[i][j] += af[i] * bf[j];
        }
        __syncthreads();
    }
#pragma unroll
    for (int i = 0; i < 8; i++) {
        int row = m0 + ty + 16 * i;
        if (row >= M) continue;
        float di = rsqrtf((float)(deg[row] + 1));
#pragma unroll
        for (int j = 0; j < 8; j++) {
            int cg = tx + 16 * j;
            C[(size_t)row * 128 + cg] = fmaxf(acc[i][j] + bias[cg], 0.f) * di;
        }
    }
}

// ---------------- GEMM2 + gates + projection ----------------
// G = agg @ Wcat + cb (cols interleaved z/t); h = (1-sig(z))*tanh(t);
// atomicAdd(aArr[row], sum h*Wout[k]); atomicAdd(bArr[row], sum h*Wout[128+k])
__global__ __launch_bounds__(256) void k_gemm_gate(const float* __restrict__ A,
                                                   const float* __restrict__ B,
                                                   const float* __restrict__ cb,
                                                   const float* __restrict__ Wout,
                                                   float* __restrict__ aArr,
                                                   float* __restrict__ bArr, int M) {
    __shared__ float As[8][128];
    __shared__ float Bs[8][128];
    const int m0 = blockIdx.x * 128;
    const int n0 = blockIdx.y * 128;
    const int tid = threadIdx.x;
    const int tx = tid & 15;
    const int ty = tid >> 4;
    float acc[8][8];
#pragma unroll
    for (int i = 0; i < 8; i++)
#pragma unroll
        for (int j = 0; j < 8; j++) acc[i][j] = 0.f;

    for (int k0 = 0; k0 < 128; k0 += 8) {
        {
            int m = tid >> 1, kk = (tid & 1) * 4;
            float4 av = make_float4(0.f, 0.f, 0.f, 0.f);
            if (m0 + m < M) av = *(const float4*)&A[(size_t)(m0 + m) * 128 + k0 + kk];
            As[kk + 0][m] = av.x; As[kk + 1][m] = av.y;
            As[kk + 2][m] = av.z; As[kk + 3][m] = av.w;
        }
        {
            int kb = tid >> 5, n = (tid & 31) * 4;
            float4 bv = *(const float4*)&B[(size_t)(k0 + kb) * 256 + n0 + n];
            *(float4*)&Bs[kb][n] = bv;
        }
        __syncthreads();
#pragma unroll
        for (int kk = 0; kk < 8; kk++) {
            float af[8], bf[8];
#pragma unroll
            for (int i = 0; i < 8; i++) af[i] = As[kk][ty + 16 * i];
#pragma unroll
            for (int j = 0; j < 8; j++) bf[j] = Bs[kk][tx + 16 * j];
#pragma unroll
            for (int i = 0; i < 8; i++)
#pragma unroll
                for (int j = 0; j < 8; j++) acc[i][j] += af[i] * bf[j];
        }
        __syncthreads();
    }
    // epilogue: cols n0+tx+16j; adjacent cols (z at even, t at odd) sit in lanes tx, tx^1
#pragma unroll
    for (int i = 0; i < 8; i++) {
        int row = m0 + ty + 16 * i;
        bool live = (row < M);
        float pa = 0.f, pb = 0.f;
#pragma unroll
        for (int j = 0; j < 8; j++) {
            int col = n0 + tx + 16 * j;
            float val = acc[i][j] + cb[col];
            bool odd = (col & 1);
            float s = odd ? tanhf(val) : (1.f / (1.f + expf(-val)));
            float partner = __shfl_xor(s, 1);
            if (!odd) {
                int k = col >> 1;
                float h = (1.f - s) * partner;   // (1-z)*tanh(t)
                pa += h * Wout[k];
                pb += h * Wout[128 + k];
            }
        }
#pragma unroll
        for (int off = 1; off < 16; off <<= 1) {
            pa += __shfl_xor(pa, off);
            pb += __shfl_xor(pb, off);
        }
        if (live && tx == 0) {
            atomicAdd(&aArr[row], pa);
            atomicAdd(&bArr[row], pb);
        }
    }
}

// ---------------- scan (3-pass) for CSR rowptr ----------------
__global__ void k_scan_a(const int* __restrict__ deg, int* __restrict__ partial) {
    __shared__ int s[256];
    int i = blockIdx.x * 256 + threadIdx.x;
    s[threadIdx.x] = (i < NN) ? deg[i] : 0;
    __syncthreads();
    for (int off = 128; off > 0; off >>= 1) {
        if (threadIdx.x < off) s[threadIdx.x] += s[threadIdx.x + off];
        __syncthreads();
    }
    if (threadIdx.x == 0) partial[blockIdx.x] = s[0];
}

__global__ void k_scan_b(const int* __restrict__ partial, int* __restrict__ partoff, int nb) {
    __shared__ int s[256];
    int v = (threadIdx.x < nb) ? partial[threadIdx.x] : 0;
    s[threadIdx.x] = v;
    __syncthreads();
    for (int off = 1; off < 256; off <<= 1) {
        int t = (threadIdx.x >= off) ? s[threadIdx.x - off] : 0;
        __syncthreads();
        s[threadIdx.x] += t;
        __syncthreads();
    }
    partoff[threadIdx.x] = s[threadIdx.x] - v;  // exclusive
}

__global__ void k_scan_c(const int* __restrict__ deg, const int* __restrict__ partoff,
                         int* __restrict__ rowptr, int* __restrict__ cursor) {
    __shared__ int s[256];
    int i = blockIdx.x * 256 + threadIdx.x;
    int v = (i < NN) ? deg[i] : 0;
    s[threadIdx.x] = v;
    __syncthreads();
    for (int off = 1; off < 256; off <<= 1) {
        int t = (threadIdx.x >= off) ? s[threadIdx.x - off] : 0;
        __syncthreads();
        s[threadIdx.x] += t;
        __syncthreads();
    }
    int excl = s[threadIdx.x] - v + partoff[blockIdx.x];
    if (i < NN) { rowptr[i] = excl; cursor[i] = excl; }
    if (i == 0) rowptr[NN] = EE;
}

__global__ void k_fill(const int* __restrict__ ei, int* __restrict__ cursor,
                       int* __restrict__ col) {
    int e = blockIdx.x * 256 + threadIdx.x;
    if (e < EE) {
        int d = ei[EE + e];
        int p = atomicAdd(&cursor[d], 1);
        col[p] = ei[e];
    }
}

// ---------------- per-node gather on xs (128 cols): one wave per node, float2/lane ----------------
__global__ __launch_bounds__(256) void k_gather(const float* __restrict__ xs,
                                                const int* __restrict__ rowptr,
                                                const int* __restrict__ col,
                                                const int* __restrict__ deg,
                                                float* __restrict__ agg) {
    int gt = blockIdx.x * 256 + threadIdx.x;
    int node = gt >> 6;
    int lane = threadIdx.x & 63;
    if (node >= NN) return;
    int beg = rowptr[node], end = rowptr[node + 1];
    float2 acc = *(const float2*)(xs + (size_t)node * 128 + lane * 2);  // self loop
    int p = beg;
    while (p < end) {
        int rem = end - p;
        int chunk = rem < 64 ? rem : 64;
        int cv = (lane < chunk) ? col[p + lane] : 0;
        int j = 0;
        for (; j + 4 <= chunk; j += 4) {
            int s0 = __shfl(cv, j + 0);
            int s1 = __shfl(cv, j + 1);
            int s2 = __shfl(cv, j + 2);
            int s3 = __shfl(cv, j + 3);
            float2 v0 = *(const float2*)(xs + (size_t)s0 * 128 + lane * 2);
            float2 v1 = *(const float2*)(xs + (size_t)s1 * 128 + lane * 2);
            float2 v2 = *(const float2*)(xs + (size_t)s2 * 128 + lane * 2);
            float2 v3 = *(const float2*)(xs + (size_t)s3 * 128 + lane * 2);
            acc.x += v0.x + v1.x + v2.x + v3.x;
            acc.y += v0.y + v1.y + v2.y + v3.y;
        }
        for (; j < chunk; j++) {
            int s = __shfl(cv, j);
            float2 v = *(const float2*)(xs + (size_t)s * 128 + lane * 2);
            acc.x += v.x;
            acc.y += v.y;
        }
        p += 64;
    }
    float di = rsqrtf((float)(deg[node] + 1));
    acc.x *= di;
    acc.y *= di;
    *(float2*)(agg + (size_t)node * 128 + lane * 2) = acc;
}

// ---------------- per-edge fused GEMM via MFMA ----------------
__global__ __launch_bounds__(256) void k_edge_mfma(const float* __restrict__ EA,
                                                   const int* __restrict__ ei,
                                                   const float* __restrict__ We,
                                                   const float* __restrict__ be,
                                                   const float* __restrict__ Wout,
                                                   const float* __restrict__ boutp,
                                                   const float* __restrict__ aArr,
                                                   const float* __restrict__ bArr,
                                                   float* __restrict__ out) {
    const int lane = threadIdx.x & 63;
    const int ln = lane & 15;
    const int q  = lane >> 4;
    const int wid = (blockIdx.x * 256 + threadIdx.x) >> 6;
    const int nw  = gridDim.x * 4;

    bf16x8 bfrag[2][8];
#pragma unroll
    for (int h = 0; h < 2; h++)
#pragma unroll
        for (int t = 0; t < 8; t++)
#pragma unroll
            for (int j = 0; j < 8; j++)
                bfrag[h][t][j] = (__bf16)We[(h * 32 + q * 8 + j) * 128 + t * 16 + ln];

    float beR[8], w3R[8];
#pragma unroll
    for (int t = 0; t < 8; t++) {
        beR[t] = be[t * 16 + ln];
        w3R[t] = Wout[256 + t * 16 + ln];
    }
    const float b0 = boutp[0];

    for (int tile = wid; tile < EE / 16; tile += nw) {
        const int e0 = tile * 16;
        const float* arow = EA + (size_t)(e0 + ln) * 64;
        float4 v0 = *(const float4*)(arow + q * 8);
        float4 v1 = *(const float4*)(arow + q * 8 + 4);
        float4 v2 = *(const float4*)(arow + 32 + q * 8);
        float4 v3 = *(const float4*)(arow + 32 + q * 8 + 4);
        bf16x8 af0, af1;
        af0[0] = (__bf16)v0.x; af0[1] = (__bf16)v0.y; af0[2] = (__bf16)v0.z; af0[3] = (__bf16)v0.w;
        af0[4] = (__bf16)v1.x; af0[5] = (__bf16)v1.y; af0[6] = (__bf16)v1.z; af0[7] = (__bf16)v1.w;
        af1[0] = (__bf16)v2.x; af1[1] = (__bf16)v2.y; af1[2] = (__bf16)v2.z; af1[3] = (__bf16)v2.w;
        af1[4] = (__bf16)v3.x; af1[5] = (__bf16)v3.y; af1[6] = (__bf16)v3.z; af1[7] = (__bf16)v3.w;

        f32x4 acc[8];
#pragma unroll
        for (int t = 0; t < 8; t++) acc[t] = (f32x4){0.f, 0.f, 0.f, 0.f};
#pragma unroll
        for (int t = 0; t < 8; t++)
            acc[t] = __builtin_amdgcn_mfma_f32_16x16x32_bf16(af0, bfrag[0][t], acc[t], 0, 0, 0);
#pragma unroll
        for (int t = 0; t < 8; t++)
            acc[t] = __builtin_amdgcn_mfma_f32_16x16x32_bf16(af1, bfrag[1][t], acc[t], 0, 0, 0);

        float part[4] = {0.f, 0.f, 0.f, 0.f};
#pragma unroll
        for (int t = 0; t < 8; t++)
#pragma unroll
            for (int r = 0; r < 4; r++) {
                float y = acc[t][r] + beR[t];
                y = fmaxf(y, 0.f);
                part[r] += y * w3R[t];
            }
#pragma unroll
        for (int off = 1; off < 16; off <<= 1) {
#pragma unroll
            for (int r = 0; r < 4; r++) part[r] += __shfl_xor(part[r], off);
        }
        if (ln < 4) {
            float c = (ln == 0) ? part[0] : (ln == 1) ? part[1] : (ln == 2) ? part[2] : part[3];
            int e = e0 + q * 4 + ln;
            out[e] = c + aArr[ei[e]] + bArr[ei[EE + e]] + b0;
        }
    }
}

extern "C" void kernel_launch(void* const* d_in, const int* in_sizes, int n_in,
                              void* d_out, int out_size, void* d_ws, size_t ws_size,
                              hipStream_t stream) {
    const float* x    = (const float*)d_in[0];
    const int*   ei   = (const int*)d_in[1];
    const float* ea   = (const float*)d_in[2];
    const float* Wn   = (const float*)d_in[3];
    const float* bn   = (const float*)d_in[4];
    const float* We   = (const float*)d_in[5];
    const float* be   = (const float*)d_in[6];
    const float* Wzc  = (const float*)d_in[7];
    const float* bzc  = (const float*)d_in[8];
    const float* Wzl  = (const float*)d_in[9];
    const float* bzl  = (const float*)d_in[10];
    const float* Whc  = (const float*)d_in[15];
    const float* bhc  = (const float*)d_in[16];
    const float* Whl  = (const float*)d_in[17];
    const float* bhl  = (const float*)d_in[18];
    const float* Wout = (const float*)d_in[19];
    const float* bout = (const float*)d_in[20];
    float* out = (float*)d_out;

    char* w = (char*)d_ws;
    auto carve = [&](size_t bytes) {
        void* p = (void*)w;
        w += (bytes + 255) / 256 * 256;
        return p;
    };
    float* xs      = (float*)carve((size_t)NN * 128 * 4);
    float* agg     = (float*)carve((size_t)NN * 128 * 4);
    float* Wcat    = (float*)carve(128 * 256 * 4);
    float* cb      = (float*)carve(256 * 4);
    int*   deg     = (int*)carve((size_t)NN * 4);
    int*   rowptr  = (int*)carve((size_t)(NN + 1) * 4);
    int*   cursor  = (int*)carve((size_t)NN * 4);
    int*   col     = (int*)carve((size_t)EE * 4);
    int*   partial = (int*)carve(256 * 4);
    int*   partoff = (int*)carve(256 * 4);
    float* aArr    = (float*)carve((size_t)NN * 4);
    float* bArr    = (float*)carve((size_t)NN * 4);

    hipMemsetAsync(deg, 0, (size_t)NN * 4, stream);
    hipMemsetAsync(aArr, 0, (size_t)NN * 4, stream);
    hipMemsetAsync(bArr, 0, (size_t)NN * 4, stream);
    k_deg<<<(EE + 255) / 256, 256, 0, stream>>>(ei, deg);
    k_wprep<<<128, 128, 0, stream>>>(Wzc, bzc, Wzl, bzl, Whc, bhc, Whl, bhl, Wcat, cb);

    // xs = relu(x @ Wn + bn) * dinv[row]
    k_gemm1<<<dim3(391, 1), 256, 0, stream>>>(x, Wn, bn, deg, xs, NN);

    // CSR build
    const int NB = (NN + 255) / 256;  // 196
    k_scan_a<<<NB, 256, 0, stream>>>(deg, partial);
    k_scan_b<<<1, 256, 0, stream>>>(partial, partoff, NB);
    k_scan_c<<<NB, 256, 0, stream>>>(deg, partoff, rowptr, cursor);
    k_fill<<<(EE + 255) / 256, 256, 0, stream>>>(ei, cursor, col);

    // agg = dinv[row] * (sum_in xs[src] + xs[row])
    k_gather<<<(NN * 64 + 255) / 256, 256, 0, stream>>>(xs, rowptr, col, deg, agg);

    // gates + projection fused into GEMM2 epilogue -> aArr, bArr
    k_gemm_gate<<<dim3(391, 2), 256, 0, stream>>>(agg, Wcat, cb, Wout, aArr, bArr, NN);

    // per-edge fused output
    k_edge_mfma<<<1024, 256, 0, stream>>>(ea, ei, We, be, Wout, bout, aArr, bArr, out);
}

// Round 4
// 653.863 us; speedup vs baseline: 1.4275x; 1.0000x over previous
//
#include <hip/hip_runtime.h>
#include <hip/hip_bf16.h>
#include <math.h>

#define NN 50000
#define EE 800000
// NF=128, EF=64, S=128

typedef __bf16 bf16x8 __attribute__((ext_vector_type(8)));
typedef float f32x4 __attribute__((ext_vector_type(4)));

// ---------------- deg histogram ----------------
__global__ void k_deg(const int* __restrict__ ei, int* __restrict__ deg) {
    int e = blockIdx.x * 256 + threadIdx.x;
    if (e < EE) atomicAdd(&deg[ei[EE + e]], 1);
}

// ---------------- weight prep (coalesced): block=i (fan-in row), thread=k (out col) ----------------
// Wcat[i][2k]=sum_j Wzc[i][j]Wzl[j][k]; Wcat[i][2k+1]= same with Whc/Whl; cb = fused bias
__global__ void k_wprep(const float* __restrict__ Wzc, const float* __restrict__ bzc,
                        const float* __restrict__ Wzl, const float* __restrict__ bzl,
                        const float* __restrict__ Whc, const float* __restrict__ bhc,
                        const float* __restrict__ Whl, const float* __restrict__ bhl,
                        float* __restrict__ Wcat, float* __restrict__ cb) {
    int i = blockIdx.x;      // 0..127 (uniform -> scalar loads of Wzc/Whc)
    int k = threadIdx.x;     // 0..127 (coalesced over Wzl/Whl)
    float sz = 0.f, sh = 0.f;
    for (int j = 0; j < 128; j++) {
        sz += Wzc[i * 128 + j] * Wzl[j * 128 + k];
        sh += Whc[i * 128 + j] * Whl[j * 128 + k];
    }
    Wcat[i * 256 + 2 * k]     = sz;
    Wcat[i * 256 + 2 * k + 1] = sh;
    if (i == 0) {
        float bz = bzl[k], bh = bhl[k];
        for (int j = 0; j < 128; j++) {
            bz += bzc[j] * Wzl[j * 128 + k];
            bh += bhc[j] * Whl[j * 128 + k];
        }
        cb[2 * k]     = bz;
        cb[2 * k + 1] = bh;
    }
}

// ---------------- GEMM1: xs[M,128] = bf16( relu(x @ Wn + bn) * dinv[row] ) ----------------
__global__ __launch_bounds__(256) void k_gemm1(const float* __restrict__ A,
                                               const float* __restrict__ B,
                                               const float* __restrict__ bias,
                                               const int* __restrict__ deg,
                                               __hip_bfloat16* __restrict__ C, int M) {
    __shared__ float As[8][128];
    __shared__ float Bs[8][128];
    const int m0 = blockIdx.x * 128;
    const int tid = threadIdx.x;
    const int tx = tid & 15;
    const int ty = tid >> 4;
    float acc[8][8];
#pragma unroll
    for (int i = 0; i < 8; i++)
#pragma unroll
        for (int j = 0; j < 8; j++) acc[i][j] = 0.f;

    for (int k0 = 0; k0 < 128; k0 += 8) {
        {
            int m = tid >> 1, kk = (tid & 1) * 4;
            float4 av = make_float4(0.f, 0.f, 0.f, 0.f);
            if (m0 + m < M) av = *(const float4*)&A[(size_t)(m0 + m) * 128 + k0 + kk];
            As[kk + 0][m] = av.x; As[kk + 1][m] = av.y;
            As[kk + 2][m] = av.z; As[kk + 3][m] = av.w;
        }
        {
            int kb = tid >> 5, n = (tid & 31) * 4;
            float4 bv = *(const float4*)&B[(size_t)(k0 + kb) * 128 + n];
            *(float4*)&Bs[kb][n] = bv;
        }
        __syncthreads();
#pragma unroll
        for (int kk = 0; kk < 8; kk++) {
            float af[8], bf[8];
#pragma unroll
            for (int i = 0; i < 8; i++) af[i] = As[kk][ty + 16 * i];
#pragma unroll
            for (int j = 0; j < 8; j++) bf[j] = Bs[kk][tx + 16 * j];
#pragma unroll
            for (int i = 0; i < 8; i++)
#pragma unroll
                for (int j = 0; j < 8; j++) acc[i][j] += af[i] * bf[j];
        }
        __syncthreads();
    }
#pragma unroll
    for (int i = 0; i < 8; i++) {
        int row = m0 + ty + 16 * i;
        if (row >= M) continue;
        float di = rsqrtf((float)(deg[row] + 1));
#pragma unroll
        for (int j = 0; j < 8; j++) {
            int cg = tx + 16 * j;
            float v = fmaxf(acc[i][j] + bias[cg], 0.f) * di;
            C[(size_t)row * 128 + cg] = __float2bfloat16(v);
        }
    }
}

// ---------------- GEMM2 + gates + projection (full 256 cols per block, plain stores) ----------------
// G = agg @ Wcat + cb (cols interleaved z/t); h = (1-sig(z))*tanh(t);
// aArr[row] = sum_k h_k * Wout[k]; bArr[row] = sum_k h_k * Wout[128+k]
__global__ __launch_bounds__(256) void k_gemm_gate(const float* __restrict__ A,
                                                   const float* __restrict__ B,
                                                   const float* __restrict__ cb,
                                                   const float* __restrict__ Wout,
                                                   float* __restrict__ aArr,
                                                   float* __restrict__ bArr, int M) {
    __shared__ float As[8][64];
    __shared__ float Bs[8][256];
    const int m0 = blockIdx.x * 64;
    const int tid = threadIdx.x;
    const int tx = tid & 15;    // col lane (cols tx + 16j)
    const int ty = tid >> 4;    // row group (rows m0 + ty*4 + i)
    float acc[4][16];
#pragma unroll
    for (int i = 0; i < 4; i++)
#pragma unroll
        for (int j = 0; j < 16; j++) acc[i][j] = 0.f;

    // loop-invariant per-lane weights
    float cbR[16], wAR[16], wBR[16];
#pragma unroll
    for (int j = 0; j < 16; j++) {
        cbR[j] = cb[tx + 16 * j];
        int kk = 8 * j + (tx >> 1);
        wAR[j] = Wout[kk];
        wBR[j] = Wout[128 + kk];
    }

    for (int k0 = 0; k0 < 128; k0 += 8) {
        if (tid < 128) {
            int m = tid >> 1, kk = (tid & 1) * 4;
            int rm = m0 + m; if (rm >= M) rm = M - 1;
            float4 av = *(const float4*)&A[(size_t)rm * 128 + k0 + kk];
            As[kk + 0][m] = av.x; As[kk + 1][m] = av.y;
            As[kk + 2][m] = av.z; As[kk + 3][m] = av.w;
        }
        {
            int kb = tid >> 5, n = (tid & 31) * 8;
            float4 b0 = *(const float4*)&B[(size_t)(k0 + kb) * 256 + n];
            float4 b1 = *(const float4*)&B[(size_t)(k0 + kb) * 256 + n + 4];
            *(float4*)&Bs[kb][n] = b0;
            *(float4*)&Bs[kb][n + 4] = b1;
        }
        __syncthreads();
#pragma unroll
        for (int kk = 0; kk < 8; kk++) {
            float af[4], bf[16];
#pragma unroll
            for (int i = 0; i < 4; i++) af[i] = As[kk][ty * 4 + i];
#pragma unroll
            for (int j = 0; j < 16; j++) bf[j] = Bs[kk][tx + 16 * j];
#pragma unroll
            for (int i = 0; i < 4; i++)
#pragma unroll
                for (int j = 0; j < 16; j++) acc[i][j] += af[i] * bf[j];
        }
        __syncthreads();
    }
    // epilogue: col = tx + 16j; even col (tx even) = z (sigmoid), odd = t (tanh)
    const bool odd = (tx & 1);
#pragma unroll
    for (int i = 0; i < 4; i++) {
        int row = m0 + ty * 4 + i;
        float pa = 0.f, pb = 0.f;
#pragma unroll
        for (int j = 0; j < 16; j++) {
            float val = acc[i][j] + cbR[j];
            val = fminf(fmaxf(val, -30.f), 30.f);
            float s;
            if (odd) {  // tanh via exp
                float e2 = __expf(2.f * val);
                s = (e2 - 1.f) / (e2 + 1.f);
            } else {    // sigmoid
                s = 1.f / (1.f + __expf(-val));
            }
            float partner = __shfl_xor(s, 1);
            if (!odd) {
                float h = (1.f - s) * partner;   // (1-z)*tanh(t)
                pa += h * wAR[j];
                pb += h * wBR[j];
            }
        }
        // reduce across even lanes within the 16-lane group
        pa += __shfl_xor(pa, 2); pb += __shfl_xor(pb, 2);
        pa += __shfl_xor(pa, 4); pb += __shfl_xor(pb, 4);
        pa += __shfl_xor(pa, 8); pb += __shfl_xor(pb, 8);
        if (tx == 0 && row < M) {
            aArr[row] = pa;
            bArr[row] = pb;
        }
    }
}

// ---------------- scan (3-pass) for CSR rowptr ----------------
__global__ void k_scan_a(const int* __restrict__ deg, int* __restrict__ partial) {
    __shared__ int s[256];
    int i = blockIdx.x * 256 + threadIdx.x;
    s[threadIdx.x] = (i < NN) ? deg[i] : 0;
    __syncthreads();
    for (int off = 128; off > 0; off >>= 1) {
        if (threadIdx.x < off) s[threadIdx.x] += s[threadIdx.x + off];
        __syncthreads();
    }
    if (threadIdx.x == 0) partial[blockIdx.x] = s[0];
}

__global__ void k_scan_b(const int* __restrict__ partial, int* __restrict__ partoff, int nb) {
    __shared__ int s[256];
    int v = (threadIdx.x < nb) ? partial[threadIdx.x] : 0;
    s[threadIdx.x] = v;
    __syncthreads();
    for (int off = 1; off < 256; off <<= 1) {
        int t = (threadIdx.x >= off) ? s[threadIdx.x - off] : 0;
        __syncthreads();
        s[threadIdx.x] += t;
        __syncthreads();
    }
    partoff[threadIdx.x] = s[threadIdx.x] - v;  // exclusive
}

__global__ void k_scan_c(const int* __restrict__ deg, const int* __restrict__ partoff,
                         int* __restrict__ rowptr, int* __restrict__ cursor) {
    __shared__ int s[256];
    int i = blockIdx.x * 256 + threadIdx.x;
    int v = (i < NN) ? deg[i] : 0;
    s[threadIdx.x] = v;
    __syncthreads();
    for (int off = 1; off < 256; off <<= 1) {
        int t = (threadIdx.x >= off) ? s[threadIdx.x - off] : 0;
        __syncthreads();
        s[threadIdx.x] += t;
        __syncthreads();
    }
    int excl = s[threadIdx.x] - v + partoff[blockIdx.x];
    if (i < NN) { rowptr[i] = excl; cursor[i] = excl; }
    if (i == 0) rowptr[NN] = EE;
}

__global__ void k_fill(const int* __restrict__ ei, int* __restrict__ cursor,
                       int* __restrict__ col) {
    int e = blockIdx.x * 256 + threadIdx.x;
    if (e < EE) {
        int d = ei[EE + e];
        int p = atomicAdd(&cursor[d], 1);
        col[p] = ei[e];
    }
}

// ---------------- per-node gather on bf16 xs: one wave per node, uint (2 bf16) per lane ----------------
__global__ __launch_bounds__(256) void k_gather(const unsigned int* __restrict__ xsu,
                                                const int* __restrict__ rowptr,
                                                const int* __restrict__ col,
                                                const int* __restrict__ deg,
                                                float* __restrict__ agg) {
    int gt = blockIdx.x * 256 + threadIdx.x;
    int node = gt >> 6;
    int lane = threadIdx.x & 63;
    if (node >= NN) return;
    int beg = rowptr[node], end = rowptr[node + 1];
    unsigned int u = xsu[(size_t)node * 64 + lane];  // self loop
    float a0 = __uint_as_float(u << 16);
    float a1 = __uint_as_float(u & 0xFFFF0000u);
    int p = beg;
    while (p < end) {
        int rem = end - p;
        int chunk = rem < 64 ? rem : 64;
        int cv = (lane < chunk) ? col[p + lane] : 0;
        int j = 0;
        for (; j + 4 <= chunk; j += 4) {
            int s0 = __shfl(cv, j + 0);
            int s1 = __shfl(cv, j + 1);
            int s2 = __shfl(cv, j + 2);
            int s3 = __shfl(cv, j + 3);
            unsigned int u0 = xsu[(size_t)s0 * 64 + lane];
            unsigned int u1 = xsu[(size_t)s1 * 64 + lane];
            unsigned int u2 = xsu[(size_t)s2 * 64 + lane];
            unsigned int u3 = xsu[(size_t)s3 * 64 + lane];
            a0 += __uint_as_float(u0 << 16) + __uint_as_float(u1 << 16)
                + __uint_as_float(u2 << 16) + __uint_as_float(u3 << 16);
            a1 += __uint_as_float(u0 & 0xFFFF0000u) + __uint_as_float(u1 & 0xFFFF0000u)
                + __uint_as_float(u2 & 0xFFFF0000u) + __uint_as_float(u3 & 0xFFFF0000u);
        }
        for (; j < chunk; j++) {
            int s = __shfl(cv, j);
            unsigned int uv = xsu[(size_t)s * 64 + lane];
            a0 += __uint_as_float(uv << 16);
            a1 += __uint_as_float(uv & 0xFFFF0000u);
        }
        p += 64;
    }
    float di = rsqrtf((float)(deg[node] + 1));
    *(float2*)(agg + (size_t)node * 128 + lane * 2) = make_float2(a0 * di, a1 * di);
}

// ---------------- per-edge fused GEMM via MFMA ----------------
__global__ __launch_bounds__(256) void k_edge_mfma(const float* __restrict__ EA,
                                                   const int* __restrict__ ei,
                                                   const float* __restrict__ We,
                                                   const float* __restrict__ be,
                                                   const float* __restrict__ Wout,
                                                   const float* __restrict__ boutp,
                                                   const float* __restrict__ aArr,
                                                   const float* __restrict__ bArr,
                                                   float* __restrict__ out) {
    const int lane = threadIdx.x & 63;
    const int ln = lane & 15;
    const int q  = lane >> 4;
    const int wid = (blockIdx.x * 256 + threadIdx.x) >> 6;
    const int nw  = gridDim.x * 4;

    bf16x8 bfrag[2][8];
#pragma unroll
    for (int h = 0; h < 2; h++)
#pragma unroll
        for (int t = 0; t < 8; t++)
#pragma unroll
            for (int j = 0; j < 8; j++)
                bfrag[h][t][j] = (__bf16)We[(h * 32 + q * 8 + j) * 128 + t * 16 + ln];

    float beR[8], w3R[8];
#pragma unroll
    for (int t = 0; t < 8; t++) {
        beR[t] = be[t * 16 + ln];
        w3R[t] = Wout[256 + t * 16 + ln];
    }
    const float b0 = boutp[0];

    for (int tile = wid; tile < EE / 16; tile += nw) {
        const int e0 = tile * 16;
        const float* arow = EA + (size_t)(e0 + ln) * 64;
        float4 v0 = *(const float4*)(arow + q * 8);
        float4 v1 = *(const float4*)(arow + q * 8 + 4);
        float4 v2 = *(const float4*)(arow + 32 + q * 8);
        float4 v3 = *(const float4*)(arow + 32 + q * 8 + 4);
        bf16x8 af0, af1;
        af0[0] = (__bf16)v0.x; af0[1] = (__bf16)v0.y; af0[2] = (__bf16)v0.z; af0[3] = (__bf16)v0.w;
        af0[4] = (__bf16)v1.x; af0[5] = (__bf16)v1.y; af0[6] = (__bf16)v1.z; af0[7] = (__bf16)v1.w;
        af1[0] = (__bf16)v2.x; af1[1] = (__bf16)v2.y; af1[2] = (__bf16)v2.z; af1[3] = (__bf16)v2.w;
        af1[4] = (__bf16)v3.x; af1[5] = (__bf16)v3.y; af1[6] = (__bf16)v3.z; af1[7] = (__bf16)v3.w;

        f32x4 acc[8];
#pragma unroll
        for (int t = 0; t < 8; t++) acc[t] = (f32x4){0.f, 0.f, 0.f, 0.f};
#pragma unroll
        for (int t = 0; t < 8; t++)
            acc[t] = __builtin_amdgcn_mfma_f32_16x16x32_bf16(af0, bfrag[0][t], acc[t], 0, 0, 0);
#pragma unroll
        for (int t = 0; t < 8; t++)
            acc[t] = __builtin_amdgcn_mfma_f32_16x16x32_bf16(af1, bfrag[1][t], acc[t], 0, 0, 0);

        float part[4] = {0.f, 0.f, 0.f, 0.f};
#pragma unroll
        for (int t = 0; t < 8; t++)
#pragma unroll
            for (int r = 0; r < 4; r++) {
                float y = acc[t][r] + beR[t];
                y = fmaxf(y, 0.f);
                part[r] += y * w3R[t];
            }
#pragma unroll
        for (int off = 1; off < 16; off <<= 1) {
#pragma unroll
            for (int r = 0; r < 4; r++) part[r] += __shfl_xor(part[r], off);
        }
        if (ln < 4) {
            float c = (ln == 0) ? part[0] : (ln == 1) ? part[1] : (ln == 2) ? part[2] : part[3];
            int e = e0 + q * 4 + ln;
            out[e] = c + aArr[ei[e]] + bArr[ei[EE + e]] + b0;
        }
    }
}

extern "C" void kernel_launch(void* const* d_in, const int* in_sizes, int n_in,
                              void* d_out, int out_size, void* d_ws, size_t ws_size,
                              hipStream_t stream) {
    const float* x    = (const float*)d_in[0];
    const int*   ei   = (const int*)d_in[1];
    const float* ea   = (const float*)d_in[2];
    const float* Wn   = (const float*)d_in[3];
    const float* bn   = (const float*)d_in[4];
    const float* We   = (const float*)d_in[5];
    const float* be   = (const float*)d_in[6];
    const float* Wzc  = (const float*)d_in[7];
    const float* bzc  = (const float*)d_in[8];
    const float* Wzl  = (const float*)d_in[9];
    const float* bzl  = (const float*)d_in[10];
    const float* Whc  = (const float*)d_in[15];
    const float* bhc  = (const float*)d_in[16];
    const float* Whl  = (const float*)d_in[17];
    const float* bhl  = (const float*)d_in[18];
    const float* Wout = (const float*)d_in[19];
    const float* bout = (const float*)d_in[20];
    float* out = (float*)d_out;

    char* w = (char*)d_ws;
    auto carve = [&](size_t bytes) {
        void* p = (void*)w;
        w += (bytes + 255) / 256 * 256;
        return p;
    };
    __hip_bfloat16* xs = (__hip_bfloat16*)carve((size_t)NN * 128 * 2);
    float* agg     = (float*)carve((size_t)NN * 128 * 4);
    float* Wcat    = (float*)carve(128 * 256 * 4);
    float* cb      = (float*)carve(256 * 4);
    int*   deg     = (int*)carve((size_t)NN * 4);
    int*   rowptr  = (int*)carve((size_t)(NN + 1) * 4);
    int*   cursor  = (int*)carve((size_t)NN * 4);
    int*   col     = (int*)carve((size_t)EE * 4);
    int*   partial = (int*)carve(256 * 4);
    int*   partoff = (int*)carve(256 * 4);
    float* aArr    = (float*)carve((size_t)NN * 4);
    float* bArr    = (float*)carve((size_t)NN * 4);

    hipMemsetAsync(deg, 0, (size_t)NN * 4, stream);
    k_deg<<<(EE + 255) / 256, 256, 0, stream>>>(ei, deg);
    k_wprep<<<128, 128, 0, stream>>>(Wzc, bzc, Wzl, bzl, Whc, bhc, Whl, bhl, Wcat, cb);

    // xs = bf16( relu(x @ Wn + bn) * dinv[row] )
    k_gemm1<<<dim3(391, 1), 256, 0, stream>>>(x, Wn, bn, deg, xs, NN);

    // CSR build
    const int NB = (NN + 255) / 256;  // 196
    k_scan_a<<<NB, 256, 0, stream>>>(deg, partial);
    k_scan_b<<<1, 256, 0, stream>>>(partial, partoff, NB);
    k_scan_c<<<NB, 256, 0, stream>>>(deg, partoff, rowptr, cursor);
    k_fill<<<(EE + 255) / 256, 256, 0, stream>>>(ei, cursor, col);

    // agg = dinv[row] * (sum_in xs[src] + xs[row])   (fp32 out)
    k_gather<<<(NN * 64 + 255) / 256, 256, 0, stream>>>((const unsigned int*)xs, rowptr, col, deg, agg);

    // gates + projection fused into GEMM2 epilogue -> aArr, bArr (plain stores)
    k_gemm_gate<<<dim3((NN + 63) / 64, 1), 256, 0, stream>>>(agg, Wcat, cb, Wout, aArr, bArr, NN);

    // per-edge fused output
    k_edge_mfma<<<2048, 256, 0, stream>>>(ea, ei, We, be, Wout, bout, aArr, bArr, out);
}

// Round 5
// 631.110 us; speedup vs baseline: 1.4790x; 1.0361x over previous
//
#include <hip/hip_runtime.h>
#include <hip/hip_bf16.h>
#include <math.h>

#define NN 50000
#define EE 800000
// NF=128, EF=64, S=128

typedef __bf16 bf16x8 __attribute__((ext_vector_type(8)));
typedef float f32x4 __attribute__((ext_vector_type(4)));

// ---------------- deg histogram ----------------
__global__ void k_deg(const int* __restrict__ ei, int* __restrict__ deg) {
    int e = blockIdx.x * 256 + threadIdx.x;
    if (e < EE) atomicAdd(&deg[ei[EE + e]], 1);
}

// ---------------- weight prep (coalesced): block=i (fan-in row), thread=k (out col) ----------------
__global__ void k_wprep(const float* __restrict__ Wzc, const float* __restrict__ bzc,
                        const float* __restrict__ Wzl, const float* __restrict__ bzl,
                        const float* __restrict__ Whc, const float* __restrict__ bhc,
                        const float* __restrict__ Whl, const float* __restrict__ bhl,
                        float* __restrict__ Wcat, float* __restrict__ cb) {
    int i = blockIdx.x;      // 0..127 (uniform -> scalar loads of Wzc/Whc)
    int k = threadIdx.x;     // 0..127 (coalesced over Wzl/Whl)
    float sz = 0.f, sh = 0.f;
    for (int j = 0; j < 128; j++) {
        sz += Wzc[i * 128 + j] * Wzl[j * 128 + k];
        sh += Whc[i * 128 + j] * Whl[j * 128 + k];
    }
    Wcat[i * 256 + 2 * k]     = sz;
    Wcat[i * 256 + 2 * k + 1] = sh;
    if (i == 0) {
        float bz = bzl[k], bh = bhl[k];
        for (int j = 0; j < 128; j++) {
            bz += bzc[j] * Wzl[j * 128 + k];
            bh += bhc[j] * Whl[j * 128 + k];
        }
        cb[2 * k]     = bz;
        cb[2 * k + 1] = bh;
    }
}

// ---------------- GEMM1: xs[M,128] = bf16( relu(x @ Wn + bn) * dinv[row] ) ----------------
__global__ __launch_bounds__(256) void k_gemm1(const float* __restrict__ A,
                                               const float* __restrict__ B,
                                               const float* __restrict__ bias,
                                               const int* __restrict__ deg,
                                               __hip_bfloat16* __restrict__ C, int M) {
    __shared__ float As[8][128];
    __shared__ float Bs[8][128];
    const int m0 = blockIdx.x * 128;
    const int tid = threadIdx.x;
    const int tx = tid & 15;
    const int ty = tid >> 4;
    float acc[8][8];
#pragma unroll
    for (int i = 0; i < 8; i++)
#pragma unroll
        for (int j = 0; j < 8; j++) acc[i][j] = 0.f;

    for (int k0 = 0; k0 < 128; k0 += 8) {
        {
            int m = tid >> 1, kk = (tid & 1) * 4;
            float4 av = make_float4(0.f, 0.f, 0.f, 0.f);
            if (m0 + m < M) av = *(const float4*)&A[(size_t)(m0 + m) * 128 + k0 + kk];
            As[kk + 0][m] = av.x; As[kk + 1][m] = av.y;
            As[kk + 2][m] = av.z; As[kk + 3][m] = av.w;
        }
        {
            int kb = tid >> 5, n = (tid & 31) * 4;
            float4 bv = *(const float4*)&B[(size_t)(k0 + kb) * 128 + n];
            *(float4*)&Bs[kb][n] = bv;
        }
        __syncthreads();
#pragma unroll
        for (int kk = 0; kk < 8; kk++) {
            float af[8], bf[8];
#pragma unroll
            for (int i = 0; i < 8; i++) af[i] = As[kk][ty + 16 * i];
#pragma unroll
            for (int j = 0; j < 8; j++) bf[j] = Bs[kk][tx + 16 * j];
#pragma unroll
            for (int i = 0; i < 8; i++)
#pragma unroll
                for (int j = 0; j < 8; j++) acc[i][j] += af[i] * bf[j];
        }
        __syncthreads();
    }
#pragma unroll
    for (int i = 0; i < 8; i++) {
        int row = m0 + ty + 16 * i;
        if (row >= M) continue;
        float di = rsqrtf((float)(deg[row] + 1));
#pragma unroll
        for (int j = 0; j < 8; j++) {
            int cg = tx + 16 * j;
            float v = fmaxf(acc[i][j] + bias[cg], 0.f) * di;
            C[(size_t)row * 128 + cg] = __float2bfloat16(v);
        }
    }
}

// ---------------- GEMM2 + gates + projection (R2-proven structure: 128x128 tiles, atomics) ----------------
// G = agg @ Wcat + cb (cols interleaved z/t); h = (1-sig(z))*tanh(t);
// atomicAdd(aArr[row], sum h*Wout[k]); atomicAdd(bArr[row], sum h*Wout[128+k])
__global__ __launch_bounds__(256) void k_gemm_gate(const float* __restrict__ A,
                                                   const float* __restrict__ B,
                                                   const float* __restrict__ cb,
                                                   const float* __restrict__ Wout,
                                                   float* __restrict__ aArr,
                                                   float* __restrict__ bArr, int M) {
    __shared__ float As[8][128];
    __shared__ float Bs[8][128];
    const int m0 = blockIdx.x * 128;
    const int n0 = blockIdx.y * 128;
    const int tid = threadIdx.x;
    const int tx = tid & 15;
    const int ty = tid >> 4;
    float acc[8][8];
#pragma unroll
    for (int i = 0; i < 8; i++)
#pragma unroll
        for (int j = 0; j < 8; j++) acc[i][j] = 0.f;

    for (int k0 = 0; k0 < 128; k0 += 8) {
        {
            int m = tid >> 1, kk = (tid & 1) * 4;
            float4 av = make_float4(0.f, 0.f, 0.f, 0.f);
            if (m0 + m < M) av = *(const float4*)&A[(size_t)(m0 + m) * 128 + k0 + kk];
            As[kk + 0][m] = av.x; As[kk + 1][m] = av.y;
            As[kk + 2][m] = av.z; As[kk + 3][m] = av.w;
        }
        {
            int kb = tid >> 5, n = (tid & 31) * 4;
            float4 bv = *(const float4*)&B[(size_t)(k0 + kb) * 256 + n0 + n];
            *(float4*)&Bs[kb][n] = bv;
        }
        __syncthreads();
#pragma unroll
        for (int kk = 0; kk < 8; kk++) {
            float af[8], bf[8];
#pragma unroll
            for (int i = 0; i < 8; i++) af[i] = As[kk][ty + 16 * i];
#pragma unroll
            for (int j = 0; j < 8; j++) bf[j] = Bs[kk][tx + 16 * j];
#pragma unroll
            for (int i = 0; i < 8; i++)
#pragma unroll
                for (int j = 0; j < 8; j++) acc[i][j] += af[i] * bf[j];
        }
        __syncthreads();
    }
    // epilogue: cols n0+tx+16j; adjacent cols (z at even, t at odd) sit in lanes tx, tx^1
#pragma unroll
    for (int i = 0; i < 8; i++) {
        int row = m0 + ty + 16 * i;
        bool live = (row < M);
        float pa = 0.f, pb = 0.f;
#pragma unroll
        for (int j = 0; j < 8; j++) {
            int col = n0 + tx + 16 * j;
            float val = acc[i][j] + cb[col];
            bool odd = (col & 1);
            float s = odd ? tanhf(val) : (1.f / (1.f + expf(-val)));
            float partner = __shfl_xor(s, 1);
            if (!odd) {
                int k = col >> 1;
                float h = (1.f - s) * partner;   // (1-z)*tanh(t)
                pa += h * Wout[k];
                pb += h * Wout[128 + k];
            }
        }
#pragma unroll
        for (int off = 1; off < 16; off <<= 1) {
            pa += __shfl_xor(pa, off);
            pb += __shfl_xor(pb, off);
        }
        if (live && tx == 0) {
            atomicAdd(&aArr[row], pa);
            atomicAdd(&bArr[row], pb);
        }
    }
}

// ---------------- scan (3-pass) for CSR rowptr ----------------
__global__ void k_scan_a(const int* __restrict__ deg, int* __restrict__ partial) {
    __shared__ int s[256];
    int i = blockIdx.x * 256 + threadIdx.x;
    s[threadIdx.x] = (i < NN) ? deg[i] : 0;
    __syncthreads();
    for (int off = 128; off > 0; off >>= 1) {
        if (threadIdx.x < off) s[threadIdx.x] += s[threadIdx.x + off];
        __syncthreads();
    }
    if (threadIdx.x == 0) partial[blockIdx.x] = s[0];
}

__global__ void k_scan_b(const int* __restrict__ partial, int* __restrict__ partoff, int nb) {
    __shared__ int s[256];
    int v = (threadIdx.x < nb) ? partial[threadIdx.x] : 0;
    s[threadIdx.x] = v;
    __syncthreads();
    for (int off = 1; off < 256; off <<= 1) {
        int t = (threadIdx.x >= off) ? s[threadIdx.x - off] : 0;
        __syncthreads();
        s[threadIdx.x] += t;
        __syncthreads();
    }
    partoff[threadIdx.x] = s[threadIdx.x] - v;  // exclusive
}

__global__ void k_scan_c(const int* __restrict__ deg, const int* __restrict__ partoff,
                         int* __restrict__ rowptr, int* __restrict__ cursor) {
    __shared__ int s[256];
    int i = blockIdx.x * 256 + threadIdx.x;
    int v = (i < NN) ? deg[i] : 0;
    s[threadIdx.x] = v;
    __syncthreads();
    for (int off = 1; off < 256; off <<= 1) {
        int t = (threadIdx.x >= off) ? s[threadIdx.x - off] : 0;
        __syncthreads();
        s[threadIdx.x] += t;
        __syncthreads();
    }
    int excl = s[threadIdx.x] - v + partoff[blockIdx.x];
    if (i < NN) { rowptr[i] = excl; cursor[i] = excl; }
    if (i == 0) rowptr[NN] = EE;
}

__global__ void k_fill(const int* __restrict__ ei, int* __restrict__ cursor,
                       int* __restrict__ col) {
    int e = blockIdx.x * 256 + threadIdx.x;
    if (e < EE) {
        int d = ei[EE + e];
        int p = atomicAdd(&cursor[d], 1);
        col[p] = ei[e];
    }
}

// ---------------- per-node gather on bf16 xs: one wave per node, uint (2 bf16) per lane ----------------
__global__ __launch_bounds__(256) void k_gather(const unsigned int* __restrict__ xsu,
                                                const int* __restrict__ rowptr,
                                                const int* __restrict__ col,
                                                const int* __restrict__ deg,
                                                float* __restrict__ agg) {
    int gt = blockIdx.x * 256 + threadIdx.x;
    int node = gt >> 6;
    int lane = threadIdx.x & 63;
    if (node >= NN) return;
    int beg = rowptr[node], end = rowptr[node + 1];
    unsigned int u = xsu[(size_t)node * 64 + lane];  // self loop
    float a0 = __uint_as_float(u << 16);
    float a1 = __uint_as_float(u & 0xFFFF0000u);
    int p = beg;
    while (p < end) {
        int rem = end - p;
        int chunk = rem < 64 ? rem : 64;
        int cv = (lane < chunk) ? col[p + lane] : 0;
        int j = 0;
        for (; j + 4 <= chunk; j += 4) {
            int s0 = __shfl(cv, j + 0);
            int s1 = __shfl(cv, j + 1);
            int s2 = __shfl(cv, j + 2);
            int s3 = __shfl(cv, j + 3);
            unsigned int u0 = xsu[(size_t)s0 * 64 + lane];
            unsigned int u1 = xsu[(size_t)s1 * 64 + lane];
            unsigned int u2 = xsu[(size_t)s2 * 64 + lane];
            unsigned int u3 = xsu[(size_t)s3 * 64 + lane];
            a0 += __uint_as_float(u0 << 16) + __uint_as_float(u1 << 16)
                + __uint_as_float(u2 << 16) + __uint_as_float(u3 << 16);
            a1 += __uint_as_float(u0 & 0xFFFF0000u) + __uint_as_float(u1 & 0xFFFF0000u)
                + __uint_as_float(u2 & 0xFFFF0000u) + __uint_as_float(u3 & 0xFFFF0000u);
        }
        for (; j < chunk; j++) {
            int s = __shfl(cv, j);
            unsigned int uv = xsu[(size_t)s * 64 + lane];
            a0 += __uint_as_float(uv << 16);
            a1 += __uint_as_float(uv & 0xFFFF0000u);
        }
        p += 64;
    }
    float di = rsqrtf((float)(deg[node] + 1));
    *(float2*)(agg + (size_t)node * 128 + lane * 2) = make_float2(a0 * di, a1 * di);
}

// ---------------- per-edge fused GEMM via MFMA ----------------
__global__ __launch_bounds__(256) void k_edge_mfma(const float* __restrict__ EA,
                                                   const int* __restrict__ ei,
                                                   const float* __restrict__ We,
                                                   const float* __restrict__ be,
                                                   const float* __restrict__ Wout,
                                                   const float* __restrict__ boutp,
                                                   const float* __restrict__ aArr,
                                                   const float* __restrict__ bArr,
                                                   float* __restrict__ out) {
    const int lane = threadIdx.x & 63;
    const int ln = lane & 15;
    const int q  = lane >> 4;
    const int wid = (blockIdx.x * 256 + threadIdx.x) >> 6;
    const int nw  = gridDim.x * 4;

    bf16x8 bfrag[2][8];
#pragma unroll
    for (int h = 0; h < 2; h++)
#pragma unroll
        for (int t = 0; t < 8; t++)
#pragma unroll
            for (int j = 0; j < 8; j++)
                bfrag[h][t][j] = (__bf16)We[(h * 32 + q * 8 + j) * 128 + t * 16 + ln];

    float beR[8], w3R[8];
#pragma unroll
    for (int t = 0; t < 8; t++) {
        beR[t] = be[t * 16 + ln];
        w3R[t] = Wout[256 + t * 16 + ln];
    }
    const float b0 = boutp[0];

    for (int tile = wid; tile < EE / 16; tile += nw) {
        const int e0 = tile * 16;
        const float* arow = EA + (size_t)(e0 + ln) * 64;
        float4 v0 = *(const float4*)(arow + q * 8);
        float4 v1 = *(const float4*)(arow + q * 8 + 4);
        float4 v2 = *(const float4*)(arow + 32 + q * 8);
        float4 v3 = *(const float4*)(arow + 32 + q * 8 + 4);
        bf16x8 af0, af1;
        af0[0] = (__bf16)v0.x; af0[1] = (__bf16)v0.y; af0[2] = (__bf16)v0.z; af0[3] = (__bf16)v0.w;
        af0[4] = (__bf16)v1.x; af0[5] = (__bf16)v1.y; af0[6] = (__bf16)v1.z; af0[7] = (__bf16)v1.w;
        af1[0] = (__bf16)v2.x; af1[1] = (__bf16)v2.y; af1[2] = (__bf16)v2.z; af1[3] = (__bf16)v2.w;
        af1[4] = (__bf16)v3.x; af1[5] = (__bf16)v3.y; af1[6] = (__bf16)v3.z; af1[7] = (__bf16)v3.w;

        f32x4 acc[8];
#pragma unroll
        for (int t = 0; t < 8; t++) acc[t] = (f32x4){0.f, 0.f, 0.f, 0.f};
#pragma unroll
        for (int t = 0; t < 8; t++)
            acc[t] = __builtin_amdgcn_mfma_f32_16x16x32_bf16(af0, bfrag[0][t], acc[t], 0, 0, 0);
#pragma unroll
        for (int t = 0; t < 8; t++)
            acc[t] = __builtin_amdgcn_mfma_f32_16x16x32_bf16(af1, bfrag[1][t], acc[t], 0, 0, 0);

        float part[4] = {0.f, 0.f, 0.f, 0.f};
#pragma unroll
        for (int t = 0; t < 8; t++)
#pragma unroll
            for (int r = 0; r < 4; r++) {
                float y = acc[t][r] + beR[t];
                y = fmaxf(y, 0.f);
                part[r] += y * w3R[t];
            }
#pragma unroll
        for (int off = 1; off < 16; off <<= 1) {
#pragma unroll
            for (int r = 0; r < 4; r++) part[r] += __shfl_xor(part[r], off);
        }
        if (ln < 4) {
            float c = (ln == 0) ? part[0] : (ln == 1) ? part[1] : (ln == 2) ? part[2] : part[3];
            int e = e0 + q * 4 + ln;
            out[e] = c + aArr[ei[e]] + bArr[ei[EE + e]] + b0;
        }
    }
}

extern "C" void kernel_launch(void* const* d_in, const int* in_sizes, int n_in,
                              void* d_out, int out_size, void* d_ws, size_t ws_size,
                              hipStream_t stream) {
    const float* x    = (const float*)d_in[0];
    const int*   ei   = (const int*)d_in[1];
    const float* ea   = (const float*)d_in[2];
    const float* Wn   = (const float*)d_in[3];
    const float* bn   = (const float*)d_in[4];
    const float* We   = (const float*)d_in[5];
    const float* be   = (const float*)d_in[6];
    const float* Wzc  = (const float*)d_in[7];
    const float* bzc  = (const float*)d_in[8];
    const float* Wzl  = (const float*)d_in[9];
    const float* bzl  = (const float*)d_in[10];
    const float* Whc  = (const float*)d_in[15];
    const float* bhc  = (const float*)d_in[16];
    const float* Whl  = (const float*)d_in[17];
    const float* bhl  = (const float*)d_in[18];
    const float* Wout = (const float*)d_in[19];
    const float* bout = (const float*)d_in[20];
    float* out = (float*)d_out;

    char* w = (char*)d_ws;
    auto carve = [&](size_t bytes) {
        void* p = (void*)w;
        w += (bytes + 255) / 256 * 256;
        return p;
    };
    __hip_bfloat16* xs = (__hip_bfloat16*)carve((size_t)NN * 128 * 2);
    float* agg     = (float*)carve((size_t)NN * 128 * 4);
    float* Wcat    = (float*)carve(128 * 256 * 4);
    float* cb      = (float*)carve(256 * 4);
    int*   deg     = (int*)carve((size_t)NN * 4);
    int*   rowptr  = (int*)carve((size_t)(NN + 1) * 4);
    int*   cursor  = (int*)carve((size_t)NN * 4);
    int*   col     = (int*)carve((size_t)EE * 4);
    int*   partial = (int*)carve(256 * 4);
    int*   partoff = (int*)carve(256 * 4);
    float* aArr    = (float*)carve((size_t)NN * 4);
    float* bArr    = (float*)carve((size_t)NN * 4);

    hipMemsetAsync(deg, 0, (size_t)NN * 4, stream);
    hipMemsetAsync(aArr, 0, (size_t)NN * 4, stream);
    hipMemsetAsync(bArr, 0, (size_t)NN * 4, stream);
    k_deg<<<(EE + 255) / 256, 256, 0, stream>>>(ei, deg);
    k_wprep<<<128, 128, 0, stream>>>(Wzc, bzc, Wzl, bzl, Whc, bhc, Whl, bhl, Wcat, cb);

    // xs = bf16( relu(x @ Wn + bn) * dinv[row] )
    k_gemm1<<<dim3(391, 1), 256, 0, stream>>>(x, Wn, bn, deg, xs, NN);

    // CSR build
    const int NB = (NN + 255) / 256;  // 196
    k_scan_a<<<NB, 256, 0, stream>>>(deg, partial);
    k_scan_b<<<1, 256, 0, stream>>>(partial, partoff, NB);
    k_scan_c<<<NB, 256, 0, stream>>>(deg, partoff, rowptr, cursor);
    k_fill<<<(EE + 255) / 256, 256, 0, stream>>>(ei, cursor, col);

    // agg = dinv[row] * (sum_in xs[src] + xs[row])   (fp32 out)
    k_gather<<<(NN * 64 + 255) / 256, 256, 0, stream>>>((const unsigned int*)xs, rowptr, col, deg, agg);

    // gates + projection fused into GEMM2 epilogue -> aArr, bArr (atomic, 2 blocks/node)
    k_gemm_gate<<<dim3(391, 2), 256, 0, stream>>>(agg, Wcat, cb, Wout, aArr, bArr, NN);

    // per-edge fused output
    k_edge_mfma<<<2048, 256, 0, stream>>>(ea, ei, We, be, Wout, bout, aArr, bArr, out);
}

// Round 6
// 544.124 us; speedup vs baseline: 1.7155x; 1.1599x over previous
//
#include <hip/hip_runtime.h>
#include <hip/hip_bf16.h>
#include <math.h>

#define NN 50000
#define EE 800000
// NF=128, EF=64, S=128; NN/16 = 3125 row-tiles exactly

typedef __bf16 bf16x8 __attribute__((ext_vector_type(8)));
typedef float f32x4 __attribute__((ext_vector_type(4)));
typedef unsigned int u32x4 __attribute__((ext_vector_type(4)));

// ---------------- deg histogram ----------------
__global__ void k_deg(const int* __restrict__ ei, int* __restrict__ deg) {
    int e = blockIdx.x * 256 + threadIdx.x;
    if (e < EE) atomicAdd(&deg[ei[EE + e]], 1);
}

// ---------------- weight prep (coalesced): block=i (fan-in row), thread=k (out col) ----------------
__global__ void k_wprep(const float* __restrict__ Wzc, const float* __restrict__ bzc,
                        const float* __restrict__ Wzl, const float* __restrict__ bzl,
                        const float* __restrict__ Whc, const float* __restrict__ bhc,
                        const float* __restrict__ Whl, const float* __restrict__ bhl,
                        float* __restrict__ Wcat, float* __restrict__ cb) {
    int i = blockIdx.x;      // 0..127 (uniform -> scalar loads of Wzc/Whc)
    int k = threadIdx.x;     // 0..127 (coalesced over Wzl/Whl)
    float sz = 0.f, sh = 0.f;
    for (int j = 0; j < 128; j++) {
        sz += Wzc[i * 128 + j] * Wzl[j * 128 + k];
        sh += Whc[i * 128 + j] * Whl[j * 128 + k];
    }
    Wcat[i * 256 + 2 * k]     = sz;
    Wcat[i * 256 + 2 * k + 1] = sh;
    if (i == 0) {
        float bz = bzl[k], bh = bhl[k];
        for (int j = 0; j < 128; j++) {
            bz += bzc[j] * Wzl[j * 128 + k];
            bh += bhc[j] * Whl[j * 128 + k];
        }
        cb[2 * k]     = bz;
        cb[2 * k + 1] = bh;
    }
}

// ---------------- GEMM1 via MFMA: xs[N,128] = bf16( relu(x @ Wn + bn) * dinv ) ----------------
// One wave per (16-row, 64-col-half) tile; Wn half held in 16 loop-invariant B frags.
__global__ __launch_bounds__(256) void k_g1_mfma(const float* __restrict__ x,
                                                 const float* __restrict__ Wn,
                                                 const float* __restrict__ bn,
                                                 const int* __restrict__ deg,
                                                 __hip_bfloat16* __restrict__ xs) {
    const int lane = threadIdx.x & 63;
    const int ln = lane & 15;
    const int q  = lane >> 4;
    const int wid = (blockIdx.x * 256 + threadIdx.x) >> 6;
    const int nw  = gridDim.x * 4;
    const int ch  = wid & 1;          // column half
    const int step = nw >> 1;

    bf16x8 bfrag[4][4];               // [t][kc]: B[k=kc*32+q*8+j][col=ch*64+t*16+ln]
#pragma unroll
    for (int t = 0; t < 4; t++)
#pragma unroll
        for (int kc = 0; kc < 4; kc++)
#pragma unroll
            for (int j = 0; j < 8; j++)
                bfrag[t][kc][j] = (__bf16)Wn[(kc * 32 + q * 8 + j) * 128 + ch * 64 + t * 16 + ln];
    float biasR[4];
#pragma unroll
    for (int t = 0; t < 4; t++) biasR[t] = bn[ch * 64 + t * 16 + ln];

    for (int rt = wid >> 1; rt < 3125; rt += step) {
        const int e0 = rt * 16;
        const float* arow = x + (size_t)(e0 + ln) * 128;
        bf16x8 af[4];
#pragma unroll
        for (int kc = 0; kc < 4; kc++) {
            float4 v0 = *(const float4*)(arow + kc * 32 + q * 8);
            float4 v1 = *(const float4*)(arow + kc * 32 + q * 8 + 4);
            af[kc][0] = (__bf16)v0.x; af[kc][1] = (__bf16)v0.y;
            af[kc][2] = (__bf16)v0.z; af[kc][3] = (__bf16)v0.w;
            af[kc][4] = (__bf16)v1.x; af[kc][5] = (__bf16)v1.y;
            af[kc][6] = (__bf16)v1.z; af[kc][7] = (__bf16)v1.w;
        }
        f32x4 acc[4];
#pragma unroll
        for (int t = 0; t < 4; t++) acc[t] = (f32x4){0.f, 0.f, 0.f, 0.f};
#pragma unroll
        for (int t = 0; t < 4; t++)
#pragma unroll
            for (int kc = 0; kc < 4; kc++)
                acc[t] = __builtin_amdgcn_mfma_f32_16x16x32_bf16(af[kc], bfrag[t][kc], acc[t], 0, 0, 0);

        float diR[4];
#pragma unroll
        for (int r = 0; r < 4; r++) diR[r] = rsqrtf((float)(deg[e0 + q * 4 + r] + 1));
#pragma unroll
        for (int t = 0; t < 4; t++)
#pragma unroll
            for (int r = 0; r < 4; r++) {
                float v = fmaxf(acc[t][r] + biasR[t], 0.f) * diR[r];
                xs[(size_t)(e0 + q * 4 + r) * 128 + ch * 64 + t * 16 + ln] = __float2bfloat16(v);
            }
    }
}

// ---------------- gate GEMM via MFMA + gates + projection ----------------
// G = agg @ Wcat + cb (cols interleaved z/t); h=(1-sig(z))*tanh(t);
// atomicAdd aArr[row] += sum h*Wout[k]; bArr[row] += sum h*Wout[128+k]
__global__ __launch_bounds__(256) void k_gate_mfma(const unsigned int* __restrict__ aggu,
                                                   const float* __restrict__ Wcat,
                                                   const float* __restrict__ cb,
                                                   const float* __restrict__ Wout,
                                                   float* __restrict__ aArr,
                                                   float* __restrict__ bArr) {
    const int lane = threadIdx.x & 63;
    const int ln = lane & 15;
    const int q  = lane >> 4;
    const int wid = (blockIdx.x * 256 + threadIdx.x) >> 6;
    const int nw  = gridDim.x * 4;
    const int cq  = wid & 3;          // column quarter of 256
    const int step = nw >> 2;

    bf16x8 bfrag[4][4];               // [t][kc]: Wcat[k=kc*32+q*8+j][col=cq*64+t*16+ln]
#pragma unroll
    for (int t = 0; t < 4; t++)
#pragma unroll
        for (int kc = 0; kc < 4; kc++)
#pragma unroll
            for (int j = 0; j < 8; j++)
                bfrag[t][kc][j] = (__bf16)Wcat[(kc * 32 + q * 8 + j) * 256 + cq * 64 + t * 16 + ln];

    float cbR[4], wAR[4], wBR[4];
#pragma unroll
    for (int t = 0; t < 4; t++) {
        int col = cq * 64 + t * 16 + ln;
        cbR[t] = cb[col];
        int k = col >> 1;             // meaningful on even lanes only
        wAR[t] = Wout[k];
        wBR[t] = Wout[128 + k];
    }
    const bool odd = (ln & 1);

    for (int rt = wid >> 2; rt < 3125; rt += step) {
        const int e0 = rt * 16;
        const u32x4* arow = (const u32x4*)aggu + (size_t)(e0 + ln) * 16;
        bf16x8 af[4];
#pragma unroll
        for (int kc = 0; kc < 4; kc++) {
            u32x4 uv = arow[kc * 4 + q];
            af[kc] = __builtin_bit_cast(bf16x8, uv);
        }
        f32x4 acc[4];
#pragma unroll
        for (int t = 0; t < 4; t++) acc[t] = (f32x4){0.f, 0.f, 0.f, 0.f};
#pragma unroll
        for (int t = 0; t < 4; t++)
#pragma unroll
            for (int kc = 0; kc < 4; kc++)
                acc[t] = __builtin_amdgcn_mfma_f32_16x16x32_bf16(af[kc], bfrag[t][kc], acc[t], 0, 0, 0);

        float pa[4] = {0.f, 0.f, 0.f, 0.f};
        float pb[4] = {0.f, 0.f, 0.f, 0.f};
#pragma unroll
        for (int t = 0; t < 4; t++)
#pragma unroll
            for (int r = 0; r < 4; r++) {
                float val = acc[t][r] + cbR[t];
                float s = odd ? tanhf(val) : (1.f / (1.f + expf(-val)));
                float partner = __shfl_xor(s, 1);
                if (!odd) {
                    float h = (1.f - s) * partner;   // (1-z)*tanh(t)
                    pa[r] += h * wAR[t];
                    pb[r] += h * wBR[t];
                }
            }
#pragma unroll
        for (int off = 1; off < 16; off <<= 1) {
#pragma unroll
            for (int r = 0; r < 4; r++) {
                pa[r] += __shfl_xor(pa[r], off);
                pb[r] += __shfl_xor(pb[r], off);
            }
        }
        if (ln < 4) {
            float v = (ln == 0) ? pa[0] : (ln == 1) ? pa[1] : (ln == 2) ? pa[2] : pa[3];
            atomicAdd(&aArr[e0 + q * 4 + ln], v);
        } else if (ln < 8) {
            int r = ln - 4;
            float v = (r == 0) ? pb[0] : (r == 1) ? pb[1] : (r == 2) ? pb[2] : pb[3];
            atomicAdd(&bArr[e0 + q * 4 + r], v);
        }
    }
}

// ---------------- scan (3-pass) for CSR rowptr ----------------
__global__ void k_scan_a(const int* __restrict__ deg, int* __restrict__ partial) {
    __shared__ int s[256];
    int i = blockIdx.x * 256 + threadIdx.x;
    s[threadIdx.x] = (i < NN) ? deg[i] : 0;
    __syncthreads();
    for (int off = 128; off > 0; off >>= 1) {
        if (threadIdx.x < off) s[threadIdx.x] += s[threadIdx.x + off];
        __syncthreads();
    }
    if (threadIdx.x == 0) partial[blockIdx.x] = s[0];
}

__global__ void k_scan_b(const int* __restrict__ partial, int* __restrict__ partoff, int nb) {
    __shared__ int s[256];
    int v = (threadIdx.x < nb) ? partial[threadIdx.x] : 0;
    s[threadIdx.x] = v;
    __syncthreads();
    for (int off = 1; off < 256; off <<= 1) {
        int t = (threadIdx.x >= off) ? s[threadIdx.x - off] : 0;
        __syncthreads();
        s[threadIdx.x] += t;
        __syncthreads();
    }
    partoff[threadIdx.x] = s[threadIdx.x] - v;  // exclusive
}

__global__ void k_scan_c(const int* __restrict__ deg, const int* __restrict__ partoff,
                         int* __restrict__ rowptr, int* __restrict__ cursor) {
    __shared__ int s[256];
    int i = blockIdx.x * 256 + threadIdx.x;
    int v = (i < NN) ? deg[i] : 0;
    s[threadIdx.x] = v;
    __syncthreads();
    for (int off = 1; off < 256; off <<= 1) {
        int t = (threadIdx.x >= off) ? s[threadIdx.x - off] : 0;
        __syncthreads();
        s[threadIdx.x] += t;
        __syncthreads();
    }
    int excl = s[threadIdx.x] - v + partoff[blockIdx.x];
    if (i < NN) { rowptr[i] = excl; cursor[i] = excl; }
    if (i == 0) rowptr[NN] = EE;
}

__global__ void k_fill(const int* __restrict__ ei, int* __restrict__ cursor,
                       int* __restrict__ col) {
    int e = blockIdx.x * 256 + threadIdx.x;
    if (e < EE) {
        int d = ei[EE + e];
        int p = atomicAdd(&cursor[d], 1);
        col[p] = ei[e];
    }
}

// ---------------- per-node gather on bf16 xs: one wave per node; emits packed-bf16 agg ----------------
__global__ __launch_bounds__(256) void k_gather(const unsigned int* __restrict__ xsu,
                                                const int* __restrict__ rowptr,
                                                const int* __restrict__ col,
                                                const int* __restrict__ deg,
                                                unsigned int* __restrict__ aggu) {
    int gt = blockIdx.x * 256 + threadIdx.x;
    int node = gt >> 6;
    int lane = threadIdx.x & 63;
    if (node >= NN) return;
    int beg = rowptr[node], end = rowptr[node + 1];
    unsigned int u = xsu[(size_t)node * 64 + lane];  // self loop
    float a0 = __uint_as_float(u << 16);
    float a1 = __uint_as_float(u & 0xFFFF0000u);
    int p = beg;
    while (p < end) {
        int rem = end - p;
        int chunk = rem < 64 ? rem : 64;
        int cv = (lane < chunk) ? col[p + lane] : 0;
        int j = 0;
        for (; j + 4 <= chunk; j += 4) {
            int s0 = __shfl(cv, j + 0);
            int s1 = __shfl(cv, j + 1);
            int s2 = __shfl(cv, j + 2);
            int s3 = __shfl(cv, j + 3);
            unsigned int u0 = xsu[(size_t)s0 * 64 + lane];
            unsigned int u1 = xsu[(size_t)s1 * 64 + lane];
            unsigned int u2 = xsu[(size_t)s2 * 64 + lane];
            unsigned int u3 = xsu[(size_t)s3 * 64 + lane];
            a0 += __uint_as_float(u0 << 16) + __uint_as_float(u1 << 16)
                + __uint_as_float(u2 << 16) + __uint_as_float(u3 << 16);
            a1 += __uint_as_float(u0 & 0xFFFF0000u) + __uint_as_float(u1 & 0xFFFF0000u)
                + __uint_as_float(u2 & 0xFFFF0000u) + __uint_as_float(u3 & 0xFFFF0000u);
        }
        for (; j < chunk; j++) {
            int s = __shfl(cv, j);
            unsigned int uv = xsu[(size_t)s * 64 + lane];
            a0 += __uint_as_float(uv << 16);
            a1 += __uint_as_float(uv & 0xFFFF0000u);
        }
        p += 64;
    }
    float di = rsqrtf((float)(deg[node] + 1));
    __hip_bfloat16 b0 = __float2bfloat16(a0 * di);
    __hip_bfloat16 b1 = __float2bfloat16(a1 * di);
    unsigned int lo = *(unsigned short*)&b0;
    unsigned int hi = *(unsigned short*)&b1;
    aggu[(size_t)node * 64 + lane] = lo | (hi << 16);
}

// ---------------- per-edge fused GEMM via MFMA ----------------
__global__ __launch_bounds__(256) void k_edge_mfma(const float* __restrict__ EA,
                                                   const int* __restrict__ ei,
                                                   const float* __restrict__ We,
                                                   const float* __restrict__ be,
                                                   const float* __restrict__ Wout,
                                                   const float* __restrict__ boutp,
                                                   const float* __restrict__ aArr,
                                                   const float* __restrict__ bArr,
                                                   float* __restrict__ out) {
    const int lane = threadIdx.x & 63;
    const int ln = lane & 15;
    const int q  = lane >> 4;
    const int wid = (blockIdx.x * 256 + threadIdx.x) >> 6;
    const int nw  = gridDim.x * 4;

    bf16x8 bfrag[2][8];
#pragma unroll
    for (int h = 0; h < 2; h++)
#pragma unroll
        for (int t = 0; t < 8; t++)
#pragma unroll
            for (int j = 0; j < 8; j++)
                bfrag[h][t][j] = (__bf16)We[(h * 32 + q * 8 + j) * 128 + t * 16 + ln];

    float beR[8], w3R[8];
#pragma unroll
    for (int t = 0; t < 8; t++) {
        beR[t] = be[t * 16 + ln];
        w3R[t] = Wout[256 + t * 16 + ln];
    }
    const float b0 = boutp[0];

    for (int tile = wid; tile < EE / 16; tile += nw) {
        const int e0 = tile * 16;
        const float* arow = EA + (size_t)(e0 + ln) * 64;
        float4 v0 = *(const float4*)(arow + q * 8);
        float4 v1 = *(const float4*)(arow + q * 8 + 4);
        float4 v2 = *(const float4*)(arow + 32 + q * 8);
        float4 v3 = *(const float4*)(arow + 32 + q * 8 + 4);
        bf16x8 af0, af1;
        af0[0] = (__bf16)v0.x; af0[1] = (__bf16)v0.y; af0[2] = (__bf16)v0.z; af0[3] = (__bf16)v0.w;
        af0[4] = (__bf16)v1.x; af0[5] = (__bf16)v1.y; af0[6] = (__bf16)v1.z; af0[7] = (__bf16)v1.w;
        af1[0] = (__bf16)v2.x; af1[1] = (__bf16)v2.y; af1[2] = (__bf16)v2.z; af1[3] = (__bf16)v2.w;
        af1[4] = (__bf16)v3.x; af1[5] = (__bf16)v3.y; af1[6] = (__bf16)v3.z; af1[7] = (__bf16)v3.w;

        f32x4 acc[8];
#pragma unroll
        for (int t = 0; t < 8; t++) acc[t] = (f32x4){0.f, 0.f, 0.f, 0.f};
#pragma unroll
        for (int t = 0; t < 8; t++)
            acc[t] = __builtin_amdgcn_mfma_f32_16x16x32_bf16(af0, bfrag[0][t], acc[t], 0, 0, 0);
#pragma unroll
        for (int t = 0; t < 8; t++)
            acc[t] = __builtin_amdgcn_mfma_f32_16x16x32_bf16(af1, bfrag[1][t], acc[t], 0, 0, 0);

        float part[4] = {0.f, 0.f, 0.f, 0.f};
#pragma unroll
        for (int t = 0; t < 8; t++)
#pragma unroll
            for (int r = 0; r < 4; r++) {
                float y = acc[t][r] + beR[t];
                y = fmaxf(y, 0.f);
                part[r] += y * w3R[t];
            }
#pragma unroll
        for (int off = 1; off < 16; off <<= 1) {
#pragma unroll
            for (int r = 0; r < 4; r++) part[r] += __shfl_xor(part[r], off);
        }
        if (ln < 4) {
            float c = (ln == 0) ? part[0] : (ln == 1) ? part[1] : (ln == 2) ? part[2] : part[3];
            int e = e0 + q * 4 + ln;
            out[e] = c + aArr[ei[e]] + bArr[ei[EE + e]] + b0;
        }
    }
}

extern "C" void kernel_launch(void* const* d_in, const int* in_sizes, int n_in,
                              void* d_out, int out_size, void* d_ws, size_t ws_size,
                              hipStream_t stream) {
    const float* x    = (const float*)d_in[0];
    const int*   ei   = (const int*)d_in[1];
    const float* ea   = (const float*)d_in[2];
    const float* Wn   = (const float*)d_in[3];
    const float* bn   = (const float*)d_in[4];
    const float* We   = (const float*)d_in[5];
    const float* be   = (const float*)d_in[6];
    const float* Wzc  = (const float*)d_in[7];
    const float* bzc  = (const float*)d_in[8];
    const float* Wzl  = (const float*)d_in[9];
    const float* bzl  = (const float*)d_in[10];
    const float* Whc  = (const float*)d_in[15];
    const float* bhc  = (const float*)d_in[16];
    const float* Whl  = (const float*)d_in[17];
    const float* bhl  = (const float*)d_in[18];
    const float* Wout = (const float*)d_in[19];
    const float* bout = (const float*)d_in[20];
    float* out = (float*)d_out;

    char* w = (char*)d_ws;
    auto carve = [&](size_t bytes) {
        void* p = (void*)w;
        w += (bytes + 255) / 256 * 256;
        return p;
    };
    __hip_bfloat16* xs = (__hip_bfloat16*)carve((size_t)NN * 128 * 2);
    unsigned int* aggu = (unsigned int*)carve((size_t)NN * 64 * 4);
    float* Wcat    = (float*)carve(128 * 256 * 4);
    float* cb      = (float*)carve(256 * 4);
    int*   deg     = (int*)carve((size_t)NN * 4);
    int*   rowptr  = (int*)carve((size_t)(NN + 1) * 4);
    int*   cursor  = (int*)carve((size_t)NN * 4);
    int*   col     = (int*)carve((size_t)EE * 4);
    int*   partial = (int*)carve(256 * 4);
    int*   partoff = (int*)carve(256 * 4);
    float* aArr    = (float*)carve((size_t)NN * 4);
    float* bArr    = (float*)carve((size_t)NN * 4);

    hipMemsetAsync(deg, 0, (size_t)NN * 4, stream);
    hipMemsetAsync(aArr, 0, (size_t)NN * 4, stream);
    hipMemsetAsync(bArr, 0, (size_t)NN * 4, stream);
    k_deg<<<(EE + 255) / 256, 256, 0, stream>>>(ei, deg);
    k_wprep<<<128, 128, 0, stream>>>(Wzc, bzc, Wzl, bzl, Whc, bhc, Whl, bhl, Wcat, cb);

    // xs = bf16( relu(x @ Wn + bn) * dinv[row] )   [MFMA]
    k_g1_mfma<<<384, 256, 0, stream>>>(x, Wn, bn, deg, xs);

    // CSR build
    const int NB = (NN + 255) / 256;  // 196
    k_scan_a<<<NB, 256, 0, stream>>>(deg, partial);
    k_scan_b<<<1, 256, 0, stream>>>(partial, partoff, NB);
    k_scan_c<<<NB, 256, 0, stream>>>(deg, partoff, rowptr, cursor);
    k_fill<<<(EE + 255) / 256, 256, 0, stream>>>(ei, cursor, col);

    // agg (packed bf16) = dinv[row] * (sum_in xs[src] + xs[row])
    k_gather<<<(NN * 64 + 255) / 256, 256, 0, stream>>>((const unsigned int*)xs, rowptr, col, deg, aggu);

    // gates + projection fused into MFMA gate GEMM -> aArr, bArr (atomic)
    k_gate_mfma<<<512, 256, 0, stream>>>(aggu, Wcat, cb, Wout, aArr, bArr);

    // per-edge fused output
    k_edge_mfma<<<2048, 256, 0, stream>>>(ea, ei, We, be, Wout, bout, aArr, bArr, out);
}

// Round 7
// 522.704 us; speedup vs baseline: 1.7858x; 1.0410x over previous
//
#include <hip/hip_runtime.h>
#include <hip/hip_bf16.h>
#include <math.h>

#define NN 50000
#define EE 800000
// NF=128, EF=64, S=128; NN/16 = 3125 row-tiles exactly; EE/256 = 3125

typedef __bf16 bf16x8 __attribute__((ext_vector_type(8)));
typedef float f32x4 __attribute__((ext_vector_type(4)));
typedef unsigned int u32x4 __attribute__((ext_vector_type(4)));

// ---------------- fused: deg histogram (blocks >=128) + weight prep (blocks 0..127) ----------------
__global__ void k_deg_wprep(const int* __restrict__ ei, int* __restrict__ deg,
                            const float* __restrict__ Wzc, const float* __restrict__ bzc,
                            const float* __restrict__ Wzl, const float* __restrict__ bzl,
                            const float* __restrict__ Whc, const float* __restrict__ bhc,
                            const float* __restrict__ Whl, const float* __restrict__ bhl,
                            float* __restrict__ Wcat, float* __restrict__ cb) {
    if (blockIdx.x < 128) {
        int i = blockIdx.x;      // fan-in row (uniform -> scalar loads of Wzc/Whc)
        int k = threadIdx.x;     // out col (coalesced over Wzl/Whl)
        if (k < 128) {
            float sz = 0.f, sh = 0.f;
            for (int j = 0; j < 128; j++) {
                sz += Wzc[i * 128 + j] * Wzl[j * 128 + k];
                sh += Whc[i * 128 + j] * Whl[j * 128 + k];
            }
            Wcat[i * 256 + 2 * k]     = sz;
            Wcat[i * 256 + 2 * k + 1] = sh;
            if (i == 0) {
                float bz = bzl[k], bh = bhl[k];
                for (int j = 0; j < 128; j++) {
                    bz += bzc[j] * Wzl[j * 128 + k];
                    bh += bhc[j] * Whl[j * 128 + k];
                }
                cb[2 * k]     = bz;
                cb[2 * k + 1] = bh;
            }
        }
    } else {
        int e = (blockIdx.x - 128) * 256 + threadIdx.x;
        if (e < EE) atomicAdd(&deg[ei[EE + e]], 1);
    }
}

// ---------------- GEMM1 via MFMA: xs[N,128] = bf16( relu(x @ Wn + bn) * dinv ) ----------------
__global__ __launch_bounds__(256) void k_g1_mfma(const float* __restrict__ x,
                                                 const float* __restrict__ Wn,
                                                 const float* __restrict__ bn,
                                                 const int* __restrict__ deg,
                                                 __hip_bfloat16* __restrict__ xs) {
    const int lane = threadIdx.x & 63;
    const int ln = lane & 15;
    const int q  = lane >> 4;
    const int wid = (blockIdx.x * 256 + threadIdx.x) >> 6;
    const int nw  = gridDim.x * 4;
    const int ch  = wid & 1;          // column half
    const int step = nw >> 1;

    bf16x8 bfrag[4][4];               // [t][kc]: B[k=kc*32+q*8+j][col=ch*64+t*16+ln]
#pragma unroll
    for (int t = 0; t < 4; t++)
#pragma unroll
        for (int kc = 0; kc < 4; kc++)
#pragma unroll
            for (int j = 0; j < 8; j++)
                bfrag[t][kc][j] = (__bf16)Wn[(kc * 32 + q * 8 + j) * 128 + ch * 64 + t * 16 + ln];
    float biasR[4];
#pragma unroll
    for (int t = 0; t < 4; t++) biasR[t] = bn[ch * 64 + t * 16 + ln];

    for (int rt = wid >> 1; rt < 3125; rt += step) {
        const int e0 = rt * 16;
        const float* arow = x + (size_t)(e0 + ln) * 128;
        bf16x8 af[4];
#pragma unroll
        for (int kc = 0; kc < 4; kc++) {
            float4 v0 = *(const float4*)(arow + kc * 32 + q * 8);
            float4 v1 = *(const float4*)(arow + kc * 32 + q * 8 + 4);
            af[kc][0] = (__bf16)v0.x; af[kc][1] = (__bf16)v0.y;
            af[kc][2] = (__bf16)v0.z; af[kc][3] = (__bf16)v0.w;
            af[kc][4] = (__bf16)v1.x; af[kc][5] = (__bf16)v1.y;
            af[kc][6] = (__bf16)v1.z; af[kc][7] = (__bf16)v1.w;
        }
        f32x4 acc[4];
#pragma unroll
        for (int t = 0; t < 4; t++) acc[t] = (f32x4){0.f, 0.f, 0.f, 0.f};
#pragma unroll
        for (int t = 0; t < 4; t++)
#pragma unroll
            for (int kc = 0; kc < 4; kc++)
                acc[t] = __builtin_amdgcn_mfma_f32_16x16x32_bf16(af[kc], bfrag[t][kc], acc[t], 0, 0, 0);

        float diR[4];
#pragma unroll
        for (int r = 0; r < 4; r++) diR[r] = rsqrtf((float)(deg[e0 + q * 4 + r] + 1));
#pragma unroll
        for (int t = 0; t < 4; t++)
#pragma unroll
            for (int r = 0; r < 4; r++) {
                float v = fmaxf(acc[t][r] + biasR[t], 0.f) * diR[r];
                xs[(size_t)(e0 + q * 4 + r) * 128 + ch * 64 + t * 16 + ln] = __float2bfloat16(v);
            }
    }
}

// ---------------- gate GEMM via MFMA + gates + projection ----------------
__global__ __launch_bounds__(256) void k_gate_mfma(const unsigned int* __restrict__ aggu,
                                                   const float* __restrict__ Wcat,
                                                   const float* __restrict__ cb,
                                                   const float* __restrict__ Wout,
                                                   float* __restrict__ aArr,
                                                   float* __restrict__ bArr) {
    const int lane = threadIdx.x & 63;
    const int ln = lane & 15;
    const int q  = lane >> 4;
    const int wid = (blockIdx.x * 256 + threadIdx.x) >> 6;
    const int nw  = gridDim.x * 4;
    const int cq  = wid & 3;          // column quarter of 256
    const int step = nw >> 2;

    bf16x8 bfrag[4][4];               // [t][kc]: Wcat[k=kc*32+q*8+j][col=cq*64+t*16+ln]
#pragma unroll
    for (int t = 0; t < 4; t++)
#pragma unroll
        for (int kc = 0; kc < 4; kc++)
#pragma unroll
            for (int j = 0; j < 8; j++)
                bfrag[t][kc][j] = (__bf16)Wcat[(kc * 32 + q * 8 + j) * 256 + cq * 64 + t * 16 + ln];

    float cbR[4], wAR[4], wBR[4];
#pragma unroll
    for (int t = 0; t < 4; t++) {
        int col = cq * 64 + t * 16 + ln;
        cbR[t] = cb[col];
        int k = col >> 1;             // meaningful on even lanes only
        wAR[t] = Wout[k];
        wBR[t] = Wout[128 + k];
    }
    const bool odd = (ln & 1);

    for (int rt = wid >> 2; rt < 3125; rt += step) {
        const int e0 = rt * 16;
        const u32x4* arow = (const u32x4*)aggu + (size_t)(e0 + ln) * 16;
        bf16x8 af[4];
#pragma unroll
        for (int kc = 0; kc < 4; kc++) {
            u32x4 uv = arow[kc * 4 + q];
            af[kc] = __builtin_bit_cast(bf16x8, uv);
        }
        f32x4 acc[4];
#pragma unroll
        for (int t = 0; t < 4; t++) acc[t] = (f32x4){0.f, 0.f, 0.f, 0.f};
#pragma unroll
        for (int t = 0; t < 4; t++)
#pragma unroll
            for (int kc = 0; kc < 4; kc++)
                acc[t] = __builtin_amdgcn_mfma_f32_16x16x32_bf16(af[kc], bfrag[t][kc], acc[t], 0, 0, 0);

        float pa[4] = {0.f, 0.f, 0.f, 0.f};
        float pb[4] = {0.f, 0.f, 0.f, 0.f};
#pragma unroll
        for (int t = 0; t < 4; t++)
#pragma unroll
            for (int r = 0; r < 4; r++) {
                float val = acc[t][r] + cbR[t];
                float s = odd ? tanhf(val) : (1.f / (1.f + expf(-val)));
                float partner = __shfl_xor(s, 1);
                if (!odd) {
                    float h = (1.f - s) * partner;   // (1-z)*tanh(t)
                    pa[r] += h * wAR[t];
                    pb[r] += h * wBR[t];
                }
            }
#pragma unroll
        for (int off = 1; off < 16; off <<= 1) {
#pragma unroll
            for (int r = 0; r < 4; r++) {
                pa[r] += __shfl_xor(pa[r], off);
                pb[r] += __shfl_xor(pb[r], off);
            }
        }
        if (ln < 4) {
            float v = (ln == 0) ? pa[0] : (ln == 1) ? pa[1] : (ln == 2) ? pa[2] : pa[3];
            atomicAdd(&aArr[e0 + q * 4 + ln], v);
        } else if (ln < 8) {
            int r = ln - 4;
            float v = (r == 0) ? pb[0] : (r == 1) ? pb[1] : (r == 2) ? pb[2] : pb[3];
            atomicAdd(&bArr[e0 + q * 4 + r], v);
        }
    }
}

// ---------------- scan: pass A (block partials) ----------------
__global__ void k_scan_a(const int* __restrict__ deg, int* __restrict__ partial) {
    __shared__ int s[256];
    int i = blockIdx.x * 256 + threadIdx.x;
    s[threadIdx.x] = (i < NN) ? deg[i] : 0;
    __syncthreads();
    for (int off = 128; off > 0; off >>= 1) {
        if (threadIdx.x < off) s[threadIdx.x] += s[threadIdx.x + off];
        __syncthreads();
    }
    if (threadIdx.x == 0) partial[blockIdx.x] = s[0];
}

// ---------------- scan: pass C (per-block base from partials + local scan) ----------------
__global__ void k_scan_c(const int* __restrict__ deg, const int* __restrict__ partial,
                         int* __restrict__ rowptr, int* __restrict__ cursor) {
    __shared__ int s[256];
    __shared__ int ps[256];
    int i = blockIdx.x * 256 + threadIdx.x;
    int v = (i < NN) ? deg[i] : 0;
    s[threadIdx.x] = v;
    ps[threadIdx.x] = (threadIdx.x < blockIdx.x) ? partial[threadIdx.x] : 0;  // nb=196<=256
    __syncthreads();
    // reduce ps -> block base in ps[0]
    for (int off = 128; off > 0; off >>= 1) {
        if (threadIdx.x < off) ps[threadIdx.x] += ps[threadIdx.x + off];
        __syncthreads();
    }
    // inclusive scan of s
    for (int off = 1; off < 256; off <<= 1) {
        int t = (threadIdx.x >= off) ? s[threadIdx.x - off] : 0;
        __syncthreads();
        s[threadIdx.x] += t;
        __syncthreads();
    }
    int excl = s[threadIdx.x] - v + ps[0];
    if (i < NN) { rowptr[i] = excl; cursor[i] = excl; }
    if (i == 0) rowptr[NN] = EE;
}

__global__ void k_fill(const int* __restrict__ ei, int* __restrict__ cursor,
                       int* __restrict__ col) {
    int e = blockIdx.x * 256 + threadIdx.x;
    if (e < EE) {
        int d = ei[EE + e];
        int p = atomicAdd(&cursor[d], 1);
        col[p] = ei[e];
    }
}

// ---------------- per-node gather on bf16 xs: one wave per node; emits packed-bf16 agg ----------------
__global__ __launch_bounds__(256) void k_gather(const unsigned int* __restrict__ xsu,
                                                const int* __restrict__ rowptr,
                                                const int* __restrict__ col,
                                                const int* __restrict__ deg,
                                                unsigned int* __restrict__ aggu) {
    int gt = blockIdx.x * 256 + threadIdx.x;
    int node = gt >> 6;
    int lane = threadIdx.x & 63;
    if (node >= NN) return;
    int beg = rowptr[node], end = rowptr[node + 1];
    unsigned int u = xsu[(size_t)node * 64 + lane];  // self loop
    float a0 = __uint_as_float(u << 16);
    float a1 = __uint_as_float(u & 0xFFFF0000u);
    int p = beg;
    while (p < end) {
        int rem = end - p;
        int chunk = rem < 64 ? rem : 64;
        int cv = (lane < chunk) ? col[p + lane] : 0;
        int j = 0;
        for (; j + 8 <= chunk; j += 8) {
            int s0 = __shfl(cv, j + 0);
            int s1 = __shfl(cv, j + 1);
            int s2 = __shfl(cv, j + 2);
            int s3 = __shfl(cv, j + 3);
            int s4 = __shfl(cv, j + 4);
            int s5 = __shfl(cv, j + 5);
            int s6 = __shfl(cv, j + 6);
            int s7 = __shfl(cv, j + 7);
            unsigned int u0 = xsu[(size_t)s0 * 64 + lane];
            unsigned int u1 = xsu[(size_t)s1 * 64 + lane];
            unsigned int u2 = xsu[(size_t)s2 * 64 + lane];
            unsigned int u3 = xsu[(size_t)s3 * 64 + lane];
            unsigned int u4 = xsu[(size_t)s4 * 64 + lane];
            unsigned int u5 = xsu[(size_t)s5 * 64 + lane];
            unsigned int u6 = xsu[(size_t)s6 * 64 + lane];
            unsigned int u7 = xsu[(size_t)s7 * 64 + lane];
            a0 += __uint_as_float(u0 << 16) + __uint_as_float(u1 << 16)
                + __uint_as_float(u2 << 16) + __uint_as_float(u3 << 16)
                + __uint_as_float(u4 << 16) + __uint_as_float(u5 << 16)
                + __uint_as_float(u6 << 16) + __uint_as_float(u7 << 16);
            a1 += __uint_as_float(u0 & 0xFFFF0000u) + __uint_as_float(u1 & 0xFFFF0000u)
                + __uint_as_float(u2 & 0xFFFF0000u) + __uint_as_float(u3 & 0xFFFF0000u)
                + __uint_as_float(u4 & 0xFFFF0000u) + __uint_as_float(u5 & 0xFFFF0000u)
                + __uint_as_float(u6 & 0xFFFF0000u) + __uint_as_float(u7 & 0xFFFF0000u);
        }
        for (; j < chunk; j++) {
            int s = __shfl(cv, j);
            unsigned int uv = xsu[(size_t)s * 64 + lane];
            a0 += __uint_as_float(uv << 16);
            a1 += __uint_as_float(uv & 0xFFFF0000u);
        }
        p += 64;
    }
    float di = rsqrtf((float)(deg[node] + 1));
    __hip_bfloat16 b0 = __float2bfloat16(a0 * di);
    __hip_bfloat16 b1 = __float2bfloat16(a1 * di);
    unsigned int lo = *(unsigned short*)&b0;
    unsigned int hi = *(unsigned short*)&b1;
    aggu[(size_t)node * 64 + lane] = lo | (hi << 16);
}

// ---------------- per-edge fused GEMM via MFMA ----------------
__global__ __launch_bounds__(256) void k_edge_mfma(const float* __restrict__ EA,
                                                   const int* __restrict__ ei,
                                                   const float* __restrict__ We,
                                                   const float* __restrict__ be,
                                                   const float* __restrict__ Wout,
                                                   const float* __restrict__ boutp,
                                                   const float* __restrict__ aArr,
                                                   const float* __restrict__ bArr,
                                                   float* __restrict__ out) {
    const int lane = threadIdx.x & 63;
    const int ln = lane & 15;
    const int q  = lane >> 4;
    const int wid = (blockIdx.x * 256 + threadIdx.x) >> 6;
    const int nw  = gridDim.x * 4;

    bf16x8 bfrag[2][8];
#pragma unroll
    for (int h = 0; h < 2; h++)
#pragma unroll
        for (int t = 0; t < 8; t++)
#pragma unroll
            for (int j = 0; j < 8; j++)
                bfrag[h][t][j] = (__bf16)We[(h * 32 + q * 8 + j) * 128 + t * 16 + ln];

    float beR[8], w3R[8];
#pragma unroll
    for (int t = 0; t < 8; t++) {
        beR[t] = be[t * 16 + ln];
        w3R[t] = Wout[256 + t * 16 + ln];
    }
    const float b0 = boutp[0];

    for (int tile = wid; tile < EE / 16; tile += nw) {
        const int e0 = tile * 16;
        const float* arow = EA + (size_t)(e0 + ln) * 64;
        float4 v0 = *(const float4*)(arow + q * 8);
        float4 v1 = *(const float4*)(arow + q * 8 + 4);
        float4 v2 = *(const float4*)(arow + 32 + q * 8);
        float4 v3 = *(const float4*)(arow + 32 + q * 8 + 4);
        bf16x8 af0, af1;
        af0[0] = (__bf16)v0.x; af0[1] = (__bf16)v0.y; af0[2] = (__bf16)v0.z; af0[3] = (__bf16)v0.w;
        af0[4] = (__bf16)v1.x; af0[5] = (__bf16)v1.y; af0[6] = (__bf16)v1.z; af0[7] = (__bf16)v1.w;
        af1[0] = (__bf16)v2.x; af1[1] = (__bf16)v2.y; af1[2] = (__bf16)v2.z; af1[3] = (__bf16)v2.w;
        af1[4] = (__bf16)v3.x; af1[5] = (__bf16)v3.y; af1[6] = (__bf16)v3.z; af1[7] = (__bf16)v3.w;

        f32x4 acc[8];
#pragma unroll
        for (int t = 0; t < 8; t++) acc[t] = (f32x4){0.f, 0.f, 0.f, 0.f};
#pragma unroll
        for (int t = 0; t < 8; t++)
            acc[t] = __builtin_amdgcn_mfma_f32_16x16x32_bf16(af0, bfrag[0][t], acc[t], 0, 0, 0);
#pragma unroll
        for (int t = 0; t < 8; t++)
            acc[t] = __builtin_amdgcn_mfma_f32_16x16x32_bf16(af1, bfrag[1][t], acc[t], 0, 0, 0);

        float part[4] = {0.f, 0.f, 0.f, 0.f};
#pragma unroll
        for (int t = 0; t < 8; t++)
#pragma unroll
            for (int r = 0; r < 4; r++) {
                float y = acc[t][r] + beR[t];
                y = fmaxf(y, 0.f);
                part[r] += y * w3R[t];
            }
#pragma unroll
        for (int off = 1; off < 16; off <<= 1) {
#pragma unroll
            for (int r = 0; r < 4; r++) part[r] += __shfl_xor(part[r], off);
        }
        if (ln < 4) {
            float c = (ln == 0) ? part[0] : (ln == 1) ? part[1] : (ln == 2) ? part[2] : part[3];
            int e = e0 + q * 4 + ln;
            out[e] = c + aArr[ei[e]] + bArr[ei[EE + e]] + b0;
        }
    }
}

extern "C" void kernel_launch(void* const* d_in, const int* in_sizes, int n_in,
                              void* d_out, int out_size, void* d_ws, size_t ws_size,
                              hipStream_t stream) {
    const float* x    = (const float*)d_in[0];
    const int*   ei   = (const int*)d_in[1];
    const float* ea   = (const float*)d_in[2];
    const float* Wn   = (const float*)d_in[3];
    const float* bn   = (const float*)d_in[4];
    const float* We   = (const float*)d_in[5];
    const float* be   = (const float*)d_in[6];
    const float* Wzc  = (const float*)d_in[7];
    const float* bzc  = (const float*)d_in[8];
    const float* Wzl  = (const float*)d_in[9];
    const float* bzl  = (const float*)d_in[10];
    const float* Whc  = (const float*)d_in[15];
    const float* bhc  = (const float*)d_in[16];
    const float* Whl  = (const float*)d_in[17];
    const float* bhl  = (const float*)d_in[18];
    const float* Wout = (const float*)d_in[19];
    const float* bout = (const float*)d_in[20];
    float* out = (float*)d_out;

    char* w = (char*)d_ws;
    auto carve = [&](size_t bytes) {
        void* p = (void*)w;
        w += (bytes + 255) / 256 * 256;
        return p;
    };
    // zero-region: deg | aArr | bArr contiguous (one memset covers all three)
    int*   deg     = (int*)carve((size_t)NN * 4);      // 200192 B padded
    float* aArr    = (float*)carve((size_t)NN * 4);
    float* bArr    = (float*)carve((size_t)NN * 4);
    size_t zbytes  = (size_t)((char*)(bArr + NN) - (char*)deg);
    __hip_bfloat16* xs = (__hip_bfloat16*)carve((size_t)NN * 128 * 2);
    unsigned int* aggu = (unsigned int*)carve((size_t)NN * 64 * 4);
    float* Wcat    = (float*)carve(128 * 256 * 4);
    float* cb      = (float*)carve(256 * 4);
    int*   rowptr  = (int*)carve((size_t)(NN + 1) * 4);
    int*   cursor  = (int*)carve((size_t)NN * 4);
    int*   col     = (int*)carve((size_t)EE * 4);
    int*   partial = (int*)carve(256 * 4);

    hipMemsetAsync(deg, 0, zbytes, stream);

    // deg histogram + fused-weight prep in one dispatch
    k_deg_wprep<<<128 + 3125, 256, 0, stream>>>(ei, deg, Wzc, bzc, Wzl, bzl,
                                                Whc, bhc, Whl, bhl, Wcat, cb);

    // xs = bf16( relu(x @ Wn + bn) * dinv[row] )   [MFMA]
    k_g1_mfma<<<384, 256, 0, stream>>>(x, Wn, bn, deg, xs);

    // CSR build (2-pass scan + fill)
    const int NB = (NN + 255) / 256;  // 196
    k_scan_a<<<NB, 256, 0, stream>>>(deg, partial);
    k_scan_c<<<NB, 256, 0, stream>>>(deg, partial, rowptr, cursor);
    k_fill<<<3125, 256, 0, stream>>>(ei, cursor, col);

    // agg (packed bf16) = dinv[row] * (sum_in xs[src] + xs[row])
    k_gather<<<(NN * 64 + 255) / 256, 256, 0, stream>>>((const unsigned int*)xs, rowptr, col, deg, aggu);

    // gates + projection fused into MFMA gate GEMM -> aArr, bArr (atomic)
    k_gate_mfma<<<512, 256, 0, stream>>>(aggu, Wcat, cb, Wout, aArr, bArr);

    // per-edge fused output
    k_edge_mfma<<<2048, 256, 0, stream>>>(ea, ei, We, be, Wout, bout, aArr, bArr, out);
}